// Round 3
// baseline (607.181 us; speedup 1.0000x reference)
//
#include <hip/hip_runtime.h>

typedef unsigned short u16;
typedef __bf16 bf16x8 __attribute__((ext_vector_type(8)));
typedef float f32x4 __attribute__((ext_vector_type(4)));
typedef u16 u16x4 __attribute__((ext_vector_type(4)));

__device__ __forceinline__ u16 f2bf(float v) {
    unsigned u = __float_as_uint(v);
    unsigned r = (u + 0x7fffu + ((u >> 16) & 1u)) >> 16;
    return (u16)r;
}
__device__ __forceinline__ float bf2f(u16 u) { return __uint_as_float(((unsigned)u) << 16); }

__device__ __forceinline__ void async_cp16(const u16* g, u16* l) {
    __builtin_amdgcn_global_load_lds((const __attribute__((address_space(1))) unsigned int*)g,
                                     (__attribute__((address_space(3))) unsigned int*)l, 16, 0, 0);
}

__device__ __forceinline__ void store1(float* C, long i, float v) { C[i] = v; }
__device__ __forceinline__ void store1(u16* C, long i, float v) { C[i] = f2bf(v); }

// C(MxNpad) = A(MxK) * B(Npad x K)^T (+bias[col]), store cols < n_store.
// If stats != nullptr, accumulate per-column sum/sumsq into stats[0..384)/[384..768).
template <typename OutT>
__global__ __launch_bounds__(256) void gemm_nt(
    const u16* __restrict__ A, const u16* __restrict__ B,
    OutT* __restrict__ C, const float* __restrict__ bias,
    int K, int ldc, int n_store, float* __restrict__ stats)
{
    __shared__ u16 As[128 * 32];
    __shared__ u16 Bs[128 * 32];
    __shared__ float cs[128], cs2[128];
    const int tid = threadIdx.x;
    const int lane = tid & 63;
    const int wave = tid >> 6;
    const int wm = wave >> 1, wn = wave & 1;
    const long m0 = (long)blockIdx.y * 128;
    const long n0 = (long)blockIdx.x * 128;

    if (stats && tid < 128) { cs[tid] = 0.0f; cs2[tid] = 0.0f; }

    f32x4 acc[4][4] = {};

    const int lrow = tid >> 2;          // 0..63
    const int lk = (tid & 3) << 3;      // 0,8,16,24
    const u16* Ag = A + (m0 + lrow) * (long)K + lk;
    const u16* Bg = B + (n0 + lrow) * (long)K + lk;
    u16* Asl = As + tid * 8;
    u16* Bsl = Bs + tid * 8;
    const long K64 = (long)64 * K;

    for (int k0 = 0; k0 < K; k0 += 32) {
        async_cp16(Ag + k0, Asl);
        async_cp16(Ag + k0 + K64, Asl + 2048);
        async_cp16(Bg + k0, Bsl);
        async_cp16(Bg + k0 + K64, Bsl + 2048);
        __syncthreads();
        bf16x8 af[4], bg[4];
        const int ro = (lane & 15) * 32 + ((lane >> 4) << 3);
#pragma unroll
        for (int i = 0; i < 4; i++) af[i] = *(const bf16x8*)(As + (wm * 64 + i * 16) * 32 + ro);
#pragma unroll
        for (int j = 0; j < 4; j++) bg[j] = *(const bf16x8*)(Bs + (wn * 64 + j * 16) * 32 + ro);
#pragma unroll
        for (int i = 0; i < 4; i++)
#pragma unroll
            for (int j = 0; j < 4; j++)
                acc[i][j] = __builtin_amdgcn_mfma_f32_16x16x32_bf16(af[i], bg[j], acc[i][j], 0, 0, 0);
        __syncthreads();
    }

#pragma unroll
    for (int i = 0; i < 4; i++) {
        const long row = m0 + wm * 64 + i * 16 + ((lane >> 4) << 2);
#pragma unroll
        for (int j = 0; j < 4; j++) {
            const int cl = wn * 64 + j * 16 + (lane & 15);
            const int col = (int)n0 + cl;
            if (col < n_store) {
                const float bv = bias ? bias[col] : 0.0f;
                float s = 0.0f, s2 = 0.0f;
#pragma unroll
                for (int r = 0; r < 4; r++) {
                    const float val = acc[i][j][r] + bv;
                    store1(C, (row + r) * (long)ldc + col, val);
                    s += val; s2 += val * val;
                }
                if (stats) { atomicAdd(&cs[cl], s); atomicAdd(&cs2[cl], s2); }
            }
        }
    }
    if (stats) {
        __syncthreads();
        if (tid < 128) {
            atomicAdd(&stats[n0 + tid], cs[tid]);
            atomicAdd(&stats[384 + n0 + tid], cs2[tid]);
        }
    }
}

// Split-K: P[z][M][Npad] fp32 partials. grid = (Npad/128, M/128, nsplit). kend clamped.
__global__ __launch_bounds__(256) void gemm_nt_splitk(
    const u16* __restrict__ A, const u16* __restrict__ B,
    float* __restrict__ P, int K, int Ksplit)
{
    __shared__ u16 As[128 * 32];
    __shared__ u16 Bs[128 * 32];
    const int tid = threadIdx.x;
    const int lane = tid & 63;
    const int wave = tid >> 6;
    const int wm = wave >> 1, wn = wave & 1;
    const long m0 = (long)blockIdx.y * 128;
    const long n0 = (long)blockIdx.x * 128;
    const int kbeg = blockIdx.z * Ksplit;
    const int kend = min(kbeg + Ksplit, K);
    const int Npad = gridDim.x * 128;
    const long M = (long)gridDim.y * 128;

    f32x4 acc[4][4] = {};

    const int lrow = tid >> 2;
    const int lk = (tid & 3) << 3;
    const u16* Ag = A + (m0 + lrow) * (long)K + lk;
    const u16* Bg = B + (n0 + lrow) * (long)K + lk;
    u16* Asl = As + tid * 8;
    u16* Bsl = Bs + tid * 8;
    const long K64 = (long)64 * K;

    for (int k0 = kbeg; k0 < kend; k0 += 32) {
        async_cp16(Ag + k0, Asl);
        async_cp16(Ag + k0 + K64, Asl + 2048);
        async_cp16(Bg + k0, Bsl);
        async_cp16(Bg + k0 + K64, Bsl + 2048);
        __syncthreads();
        bf16x8 af[4], bg[4];
        const int ro = (lane & 15) * 32 + ((lane >> 4) << 3);
#pragma unroll
        for (int i = 0; i < 4; i++) af[i] = *(const bf16x8*)(As + (wm * 64 + i * 16) * 32 + ro);
#pragma unroll
        for (int j = 0; j < 4; j++) bg[j] = *(const bf16x8*)(Bs + (wn * 64 + j * 16) * 32 + ro);
#pragma unroll
        for (int i = 0; i < 4; i++)
#pragma unroll
            for (int j = 0; j < 4; j++)
                acc[i][j] = __builtin_amdgcn_mfma_f32_16x16x32_bf16(af[i], bg[j], acc[i][j], 0, 0, 0);
        __syncthreads();
    }

    float* Pz = P + (long)blockIdx.z * M * Npad;
#pragma unroll
    for (int i = 0; i < 4; i++) {
        const long row = m0 + wm * 64 + i * 16 + ((lane >> 4) << 2);
#pragma unroll
        for (int j = 0; j < 4; j++) {
            const int col = (int)n0 + wn * 64 + j * 16 + (lane & 15);
#pragma unroll
            for (int r = 0; r < 4; r++)
                Pz[(row + r) * (long)Npad + col] = acc[i][j][r];
        }
    }
}

// S[i] = sum_z P[z*MN + i], fp32 out. grid = MN/1024, 4 floats/thread.
__global__ __launch_bounds__(256) void reduce_splitk_f32(
    const float* __restrict__ P, float* __restrict__ S, int nsplit, long MN)
{
    const long i = ((long)blockIdx.x * 256 + threadIdx.x) * 4;
    f32x4 s = *(const f32x4*)(P + i);
    for (int k = 1; k < nsplit; k++) s += *(const f32x4*)(P + (long)k * MN + i);
    *(f32x4*)(S + i) = s;
}

// bf16 out variant. grid = MN/1024.
__global__ __launch_bounds__(256) void reduce_splitk_bf16(
    const float* __restrict__ P, u16* __restrict__ Y, int nsplit, long MN)
{
    const long i = ((long)blockIdx.x * 256 + threadIdx.x) * 4;
    f32x4 s = *(const f32x4*)(P + i);
    for (int k = 1; k < nsplit; k++) s += *(const f32x4*)(P + (long)k * MN + i);
    u16x4 o;
#pragma unroll
    for (int c = 0; c < 4; c++) o[c] = f2bf(s[c]);
    *(u16x4*)(Y + i) = o;
}

// inputs fp32 (65536x180) -> bf16 padded (65536x192)
__global__ __launch_bounds__(192) void conv_input(const float* __restrict__ in, u16* __restrict__ out)
{
    const long r = blockIdx.x;
    const int k = threadIdx.x;
    out[r * 192 + k] = (k < 180) ? f2bf(in[r * 180 + k]) : (u16)0;
}

__global__ __launch_bounds__(192) void prep_w1t(const float* __restrict__ W1, u16* __restrict__ W1t)
{
    const int n = blockIdx.x, k = threadIdx.x;
    W1t[n * 192 + k] = (n < 360 && k < 180) ? f2bf(W1[k * 360 + n]) : (u16)0;
}

__global__ __launch_bounds__(192) void prep_w2t(const float* __restrict__ W2, u16* __restrict__ W2t)
{
    const int n = blockIdx.x, k = threadIdx.x;
    W2t[n * 192 + k] = (n < 180 && k < 180) ? f2bf(W2[k * 180 + n]) : (u16)0;
}

__global__ __launch_bounds__(640) void prep_bias(const float* __restrict__ b1, const float* __restrict__ b2,
                                                 float* __restrict__ b1p, float* __restrict__ b2p)
{
    const int i = threadIdx.x;
    if (i < 384) b1p[i] = (i < 360) ? b1[i] : 0.0f;
    else { const int j = i - 384; b2p[j] = (j < 180) ? b2[j] : 0.0f; }
}

__global__ __launch_bounds__(384) void bn_finalize(const float* __restrict__ accum,
                                                   const float* __restrict__ bn_scale,
                                                   const float* __restrict__ bn_bias,
                                                   float* __restrict__ se, float* __restrict__ be)
{
    const int ch = threadIdx.x;
    const float mean = accum[ch] * (1.0f / 65536.0f);
    const float var = accum[384 + ch] * (1.0f / 65536.0f) - mean * mean;
    const float sc = (ch < 360) ? bn_scale[ch] : 0.0f;
    const float bi = (ch < 360) ? bn_bias[ch] : 0.0f;
    const float inv = rsqrtf(var + 1e-5f);
    se[ch] = sc * inv;
    be[ch] = bi - mean * sc * inv;
}

__global__ __launch_bounds__(256) void gather_qv(
    const u16* __restrict__ x, const float* __restrict__ se, const float* __restrict__ be,
    u16* __restrict__ q, u16* __restrict__ v,
    int g, int log2ws, int log2wc, int D, int Dpad)
{
    const int n = blockIdx.y;
    const int d = blockIdx.x * 256 + threadIdx.x;
    const long oq = (long)n * Dpad + d;
    if (d >= D) { q[oq] = 0; v[oq] = 0; return; }
    const int ws = 1 << log2ws, s = ws >> 1;
    const int cc = d % 60;
    const int pp = d / 60;
    const int dh = pp >> log2ws, dw = pp & (ws - 1);
    const int wcm = (1 << log2wc) - 1;
    const int wi = n & wcm;
    const int hi = (n >> log2wc) & wcm;
    const int b = n >> (2 * log2wc);
    const int row = ((hi << log2ws) + dh + s) & 127;
    const int col = ((wi << log2ws) + dw + s) & 127;
    const int ch = 120 * g + cc;
    const long src = ((long)((b << 7) + row) * 128 + col) * 384 + ch;
    const float xq = bf2f(x[src]);
    const float xv = bf2f(x[src + 60]);
    q[oq] = f2bf(se[ch] * xq + be[ch]);
    v[oq] = f2bf(se[ch + 60] * xv + be[ch + 60]);
}

__global__ __launch_bounds__(256) void transpose_bf16(
    const u16* __restrict__ src, u16* __restrict__ dst, int R, int Ccols)
{
    __shared__ u16 t[64][65];
    const int c0 = blockIdx.x * 64, r0 = blockIdx.y * 64;
    const int tc = threadIdx.x & 63;
    const int tr = threadIdx.x >> 6;
#pragma unroll
    for (int i = 0; i < 16; i++) {
        const int r = tr + i * 4;
        t[r][tc] = src[(long)(r0 + r) * Ccols + c0 + tc];
    }
    __syncthreads();
#pragma unroll
    for (int i = 0; i < 16; i++) {
        const int r = tr + i * 4;
        dst[(long)(c0 + r) * R + r0 + tc] = t[tc][r];
    }
}

template <int VPT>
__global__ __launch_bounds__(256) void softmax_rows(float* __restrict__ S, u16* __restrict__ Sb)
{
    const int N = VPT * 256;
    const long base = (long)blockIdx.x * N;
    float* p = S + base;
    u16* pb = Sb + base;
    float v[VPT];
    float mx = -3.0e38f;
#pragma unroll
    for (int i = 0; i < VPT; i++) { v[i] = p[i * 256 + threadIdx.x]; mx = fmaxf(mx, v[i]); }
#pragma unroll
    for (int o = 32; o > 0; o >>= 1) mx = fmaxf(mx, __shfl_down(mx, o, 64));
    __shared__ float redm[4];
    if ((threadIdx.x & 63) == 0) redm[threadIdx.x >> 6] = mx;
    __syncthreads();
    mx = fmaxf(fmaxf(redm[0], redm[1]), fmaxf(redm[2], redm[3]));
    float s = 0.0f;
#pragma unroll
    for (int i = 0; i < VPT; i++) { v[i] = __expf(v[i] - mx); s += v[i]; }
#pragma unroll
    for (int o = 32; o > 0; o >>= 1) s += __shfl_down(s, o, 64);
    __shared__ float reds[4];
    if ((threadIdx.x & 63) == 0) reds[threadIdx.x >> 6] = s;
    __syncthreads();
    s = reds[0] + reds[1] + reds[2] + reds[3];
    const float inv = 1.0f / s;
#pragma unroll
    for (int i = 0; i < VPT; i++) {
        const float r = v[i] * inv;
        p[i * 256 + threadIdx.x] = r;
        pb[i * 256 + threadIdx.x] = f2bf(r);
    }
}

__global__ __launch_bounds__(256) void scatter_y(
    const u16* __restrict__ Y, u16* __restrict__ Ysp,
    int g, int log2ws, int log2wc, int D, int Dpad)
{
    const int n = blockIdx.y;
    const int d = blockIdx.x * 256 + threadIdx.x;
    if (d >= D) return;
    const int ws = 1 << log2ws, s = ws >> 1;
    const int cc = d % 60;
    const int pp = d / 60;
    const int dh = pp >> log2ws, dw = pp & (ws - 1);
    const int wcm = (1 << log2wc) - 1;
    const int wi = n & wcm;
    const int hi = (n >> log2wc) & wcm;
    const int b = n >> (2 * log2wc);
    const int row = ((hi << log2ws) + dh + s) & 127;
    const int col = ((wi << log2ws) + dw + s) & 127;
    Ysp[((long)((b << 7) + row) * 128 + col) * 192 + 60 * g + cc] = Y[(long)n * Dpad + d];
}

extern "C" void kernel_launch(void* const* d_in, const int* in_sizes, int n_in,
                              void* d_out, int out_size, void* d_ws, size_t ws_size,
                              hipStream_t stream)
{
    const float* in_x = (const float*)d_in[0];
    const float* w1  = (const float*)d_in[1];
    const float* b1  = (const float*)d_in[2];
    const float* bns = (const float*)d_in[3];
    const float* bnb = (const float*)d_in[4];
    const float* w2  = (const float*)d_in[5];
    const float* b2  = (const float*)d_in[6];
    float* out = (float*)d_out;

    char* w = (char*)d_ws;
    // region0 (33.55 MB): Abuf | qq^T partials (g1:25MB, g2:15.7MB) | PV partials (g1/g2: 31.46MB)
    //                     | atnb for g0 (33.5MB). All lifetimes disjoint in stream order.
    u16* Abuf = (u16*)w;
    float* part0 = (float*)w;
    u16* atnb0 = (u16*)w;
    size_t off = 33554432;
    // x region (50.33 MB = exactly 3 x 16.78 MB): x until g0 gather, then g0 PV partials.
    u16* x = (u16*)(w + off);
    float* partx = (float*)(w + off);
    off += 50331648;
    u16* W1t = (u16*)(w + off);  off += 147456;
    u16* W2t = (u16*)(w + off);  off += 98304;
    float* b1p = (float*)(w + off);   off += 4096;
    float* b2p = (float*)(w + off);   off += 4096;
    float* accum = (float*)(w + off); off += 4096;
    float* se = (float*)(w + off);    off += 2048;
    float* be = (float*)(w + off);    off += 2048;
    u16* q  = (u16*)(w + off);   off += 8388608;
    u16* v  = (u16*)(w + off);   off += 8388608;   // doubles as atnb for g1/g2 (v dead after transpose)
    u16* vt = (u16*)(w + off);   off += 8388608;
    u16* Yb = (u16*)(w + off);   off += 8388608;
    u16* Ysp = (u16*)(w + off);  off += 25165824;

    hipMemsetAsync(accum, 0, 4096, stream);
    hipMemsetAsync(Ysp, 0, 25165824, stream);

    conv_input<<<65536, 192, 0, stream>>>(in_x, Abuf);
    prep_w1t<<<384, 192, 0, stream>>>(w1, W1t);
    prep_w2t<<<256, 192, 0, stream>>>(w2, W2t);
    prep_bias<<<1, 640, 0, stream>>>(b1, b2, b1p, b2p);

    // conv1 (+fused BN stats): x = Abuf @ W1t^T + b1
    gemm_nt<u16><<<dim3(3, 512), 256, 0, stream>>>(Abuf, W1t, x, b1p, 192, 384, 384, accum);
    bn_finalize<<<1, 384, 0, stream>>>(accum, bns, bnb, se, be);

    const int  Ns[3]   = {4096, 1024, 256};
    const int  Ds[3]   = {960, 3840, 15360};
    const int  Dps[3]  = {1024, 3840, 15360};
    const int  l2ws[3] = {2, 3, 4};
    const int  l2wc[3] = {5, 4, 3};
    const int  nspl_qq[3] = {1, 8, 60};
    const int  nspl_pv[3] = {3, 2, 2};
    const int  kspl_pv[3] = {1376, 512, 128};   // K = N per group; g0 non-uniform (43/43/42 iters)
    const long atn_off[3] = {11796480L, 28573696L, 29622272L};

    // group order: g2, g1, g0 (so x is dead before g0's PV partials reuse its region)
    const int order[3] = {2, 1, 0};
    for (int oi = 0; oi < 3; oi++) {
        const int g = order[oi];
        const int N = Ns[g], D = Ds[g], Dp = Dps[g];
        gather_qv<<<dim3(Dp / 256, N), 256, 0, stream>>>(x, se, be, q, v, g, l2ws[g], l2wc[g], D, Dp);
        transpose_bf16<<<dim3(Dp / 64, N / 64), 256, 0, stream>>>(v, vt, N, Dp);
        float* S = out + atn_off[g];
        // S = q @ q^T
        if (nspl_qq[g] == 1) {
            gemm_nt<float><<<dim3(N / 128, N / 128), 256, 0, stream>>>(q, q, S, nullptr, Dp, N, N, nullptr);
        } else {
            gemm_nt_splitk<<<dim3(N / 128, N / 128, nspl_qq[g]), 256, 0, stream>>>(
                q, q, part0, Dp, Dp / nspl_qq[g]);
            reduce_splitk_f32<<<(long)N * N / 1024, 256, 0, stream>>>(part0, S, nspl_qq[g], (long)N * N);
        }
        u16* atnb = (g == 0) ? atnb0 : v;   // g0: region0; g1/g2: dead v slot
        if (N == 4096)      softmax_rows<16><<<N, 256, 0, stream>>>(S, atnb);
        else if (N == 1024) softmax_rows<4><<<N, 256, 0, stream>>>(S, atnb);
        else                softmax_rows<1><<<N, 256, 0, stream>>>(S, atnb);
        // Y = atn @ (v^T)^T via split-K
        float* pvpart = (g == 0) ? partx : part0;
        const long MN = (long)N * Dp;
        gemm_nt_splitk<<<dim3(Dp / 128, N / 128, nspl_pv[g]), 256, 0, stream>>>(
            atnb, vt, pvpart, N, kspl_pv[g]);
        reduce_splitk_bf16<<<MN / 1024, 256, 0, stream>>>(pvpart, Yb, nspl_pv[g], MN);
        scatter_y<<<dim3((D + 255) / 256, N), 256, 0, stream>>>(Yb, Ysp, g, l2ws[g], l2wc[g], D, Dp);
    }

    // conv2: out = Ysp @ W2t^T + b2
    gemm_nt<float><<<dim3(2, 512), 256, 0, stream>>>(Ysp, W2t, out, b2p, 192, 180, 180, nullptr);
}

// Round 4
// 602.175 us; speedup vs baseline: 1.0083x; 1.0083x over previous
//
#include <hip/hip_runtime.h>

typedef unsigned short u16;
typedef __bf16 bf16x8 __attribute__((ext_vector_type(8)));
typedef float f32x4 __attribute__((ext_vector_type(4)));
typedef u16 u16x4 __attribute__((ext_vector_type(4)));
typedef u16 u16x8 __attribute__((ext_vector_type(8)));

__device__ __forceinline__ u16 f2bf(float v) {
    unsigned u = __float_as_uint(v);
    unsigned r = (u + 0x7fffu + ((u >> 16) & 1u)) >> 16;
    return (u16)r;
}
__device__ __forceinline__ float bf2f(u16 u) { return __uint_as_float(((unsigned)u) << 16); }

__device__ __forceinline__ void async_cp16(const u16* g, u16* l) {
    __builtin_amdgcn_global_load_lds((const __attribute__((address_space(1))) unsigned int*)g,
                                     (__attribute__((address_space(3))) unsigned int*)l, 16, 0, 0);
}

// C(MxNpad) = A(MxK) * B(Npad x K)^T (+bias[col]), store cols < n_store.
// M%128==0, Npad%128==0, K%64==0, n_store%8==0 (u16) / %4==0 (f32).
// Epilogue re-stages C through LDS for 16B/lane coalesced stores.
template <typename OutT>
__global__ __launch_bounds__(256) void gemm_nt(
    const u16* __restrict__ A, const u16* __restrict__ B,
    OutT* __restrict__ C, const float* __restrict__ bias,
    int K, int ldc, int n_store)
{
    __shared__ char smem[16384];
    u16* As = (u16*)smem;
    u16* Bs = (u16*)(smem + 8192);
    const int tid = threadIdx.x;
    const int lane = tid & 63;
    const int wave = tid >> 6;
    const int wm = wave >> 1, wn = wave & 1;
    const long m0 = (long)blockIdx.y * 128;
    const long n0 = (long)blockIdx.x * 128;

    f32x4 acc[4][4] = {};

    const int lrow = tid >> 2;
    const int lk = (tid & 3) << 3;
    const u16* Ag = A + (m0 + lrow) * (long)K + lk;
    const u16* Bg = B + (n0 + lrow) * (long)K + lk;
    u16* Asl = As + tid * 8;
    u16* Bsl = Bs + tid * 8;
    const long K64 = (long)64 * K;

    for (int k0 = 0; k0 < K; k0 += 32) {
        async_cp16(Ag + k0, Asl);
        async_cp16(Ag + k0 + K64, Asl + 2048);
        async_cp16(Bg + k0, Bsl);
        async_cp16(Bg + k0 + K64, Bsl + 2048);
        __syncthreads();
        bf16x8 af[4], bg[4];
        const int ro = (lane & 15) * 32 + ((lane >> 4) << 3);
#pragma unroll
        for (int i = 0; i < 4; i++) af[i] = *(const bf16x8*)(As + (wm * 64 + i * 16) * 32 + ro);
#pragma unroll
        for (int j = 0; j < 4; j++) bg[j] = *(const bf16x8*)(Bs + (wn * 64 + j * 16) * 32 + ro);
#pragma unroll
        for (int i = 0; i < 4; i++)
#pragma unroll
            for (int j = 0; j < 4; j++)
                acc[i][j] = __builtin_amdgcn_mfma_f32_16x16x32_bf16(af[i], bg[j], acc[i][j], 0, 0, 0);
        __syncthreads();
    }

    float bv[4] = {0.0f, 0.0f, 0.0f, 0.0f};
    if (bias) {
#pragma unroll
        for (int j = 0; j < 4; j++) bv[j] = bias[n0 + wn * 64 + j * 16 + (lane & 15)];
    }

    if constexpr (sizeof(OutT) == 2) {
        u16* Cs = (u16*)smem;   // 64 x 128 u16 = 16 KB
        for (int c = 0; c < 2; c++) {
            __syncthreads();
            if (wm == c) {
#pragma unroll
                for (int i = 0; i < 4; i++)
#pragma unroll
                    for (int j = 0; j < 4; j++)
#pragma unroll
                        for (int r = 0; r < 4; r++) {
                            const int lr = i * 16 + ((lane >> 4) << 2) + r;
                            Cs[lr * 128 + wn * 64 + j * 16 + (lane & 15)] = f2bf(acc[i][j][r] + bv[j]);
                        }
            }
            __syncthreads();
            const int lr = tid >> 2;
            const int cg = (tid & 3) * 32;
            const long rowg = m0 + c * 64 + lr;
#pragma unroll
            for (int e = 0; e < 4; e++) {
                const int colg = cg + e * 8;
                if ((int)n0 + colg < n_store)
                    *(u16x8*)((u16*)C + rowg * (long)ldc + n0 + colg) = *(const u16x8*)(Cs + lr * 128 + colg);
            }
        }
    } else {
        float* Cs = (float*)smem;   // 32 x 128 f32 = 16 KB
        for (int c = 0; c < 4; c++) {
            __syncthreads();
            if (wm == (c >> 1)) {
#pragma unroll
                for (int ii = 0; ii < 2; ii++) {
                    const int i = (c & 1) * 2 + ii;
#pragma unroll
                    for (int j = 0; j < 4; j++)
#pragma unroll
                        for (int r = 0; r < 4; r++) {
                            const int lr = ii * 16 + ((lane >> 4) << 2) + r;
                            Cs[lr * 128 + wn * 64 + j * 16 + (lane & 15)] = acc[i][j][r] + bv[j];
                        }
                }
            }
            __syncthreads();
            const int lr = tid >> 3;
            const int cg = (tid & 7) * 16;
            const long rowg = m0 + c * 32 + lr;
#pragma unroll
            for (int e = 0; e < 4; e++) {
                const int colg = cg + e * 4;
                if ((int)n0 + colg < n_store)
                    *(f32x4*)((float*)C + rowg * (long)ldc + n0 + colg) = *(const f32x4*)(Cs + lr * 128 + colg);
            }
        }
    }
}

// Split-K: P[z][M][Npad] fp32 partials, coalesced epilogue. grid=(Npad/128, M/128, nsplit).
__global__ __launch_bounds__(256) void gemm_nt_splitk(
    const u16* __restrict__ A, const u16* __restrict__ B,
    float* __restrict__ P, int K, int Ksplit)
{
    __shared__ char smem[16384];
    u16* As = (u16*)smem;
    u16* Bs = (u16*)(smem + 8192);
    const int tid = threadIdx.x;
    const int lane = tid & 63;
    const int wave = tid >> 6;
    const int wm = wave >> 1, wn = wave & 1;
    const long m0 = (long)blockIdx.y * 128;
    const long n0 = (long)blockIdx.x * 128;
    const int kbeg = blockIdx.z * Ksplit;
    const int kend = min(kbeg + Ksplit, K);
    const int Npad = gridDim.x * 128;
    const long M = (long)gridDim.y * 128;

    f32x4 acc[4][4] = {};

    const int lrow = tid >> 2;
    const int lk = (tid & 3) << 3;
    const u16* Ag = A + (m0 + lrow) * (long)K + lk;
    const u16* Bg = B + (n0 + lrow) * (long)K + lk;
    u16* Asl = As + tid * 8;
    u16* Bsl = Bs + tid * 8;
    const long K64 = (long)64 * K;

    for (int k0 = kbeg; k0 < kend; k0 += 32) {
        async_cp16(Ag + k0, Asl);
        async_cp16(Ag + k0 + K64, Asl + 2048);
        async_cp16(Bg + k0, Bsl);
        async_cp16(Bg + k0 + K64, Bsl + 2048);
        __syncthreads();
        bf16x8 af[4], bg[4];
        const int ro = (lane & 15) * 32 + ((lane >> 4) << 3);
#pragma unroll
        for (int i = 0; i < 4; i++) af[i] = *(const bf16x8*)(As + (wm * 64 + i * 16) * 32 + ro);
#pragma unroll
        for (int j = 0; j < 4; j++) bg[j] = *(const bf16x8*)(Bs + (wn * 64 + j * 16) * 32 + ro);
#pragma unroll
        for (int i = 0; i < 4; i++)
#pragma unroll
            for (int j = 0; j < 4; j++)
                acc[i][j] = __builtin_amdgcn_mfma_f32_16x16x32_bf16(af[i], bg[j], acc[i][j], 0, 0, 0);
        __syncthreads();
    }

    float* Pz = P + (long)blockIdx.z * M * Npad;
    float* Cs = (float*)smem;
    for (int c = 0; c < 4; c++) {
        __syncthreads();
        if (wm == (c >> 1)) {
#pragma unroll
            for (int ii = 0; ii < 2; ii++) {
                const int i = (c & 1) * 2 + ii;
#pragma unroll
                for (int j = 0; j < 4; j++)
#pragma unroll
                    for (int r = 0; r < 4; r++) {
                        const int lr = ii * 16 + ((lane >> 4) << 2) + r;
                        Cs[lr * 128 + wn * 64 + j * 16 + (lane & 15)] = acc[i][j][r];
                    }
            }
        }
        __syncthreads();
        const int lr = tid >> 3;
        const int cg = (tid & 7) * 16;
        const long rowg = m0 + c * 32 + lr;
#pragma unroll
        for (int e = 0; e < 4; e++) {
            const int colg = cg + e * 4;
            *(f32x4*)(Pz + rowg * (long)Npad + n0 + colg) = *(const f32x4*)(Cs + lr * 128 + colg);
        }
    }
}

// inputs fp32 (65536x180) -> bf16 padded (65536x192)
__global__ __launch_bounds__(192) void conv_input(const float* __restrict__ in, u16* __restrict__ out)
{
    const long r = blockIdx.x;
    const int k = threadIdx.x;
    out[r * 192 + k] = (k < 180) ? f2bf(in[r * 180 + k]) : (u16)0;
}

__global__ __launch_bounds__(192) void prep_w1t(const float* __restrict__ W1, u16* __restrict__ W1t)
{
    const int n = blockIdx.x, k = threadIdx.x;
    W1t[n * 192 + k] = (n < 360 && k < 180) ? f2bf(W1[k * 360 + n]) : (u16)0;
}

__global__ __launch_bounds__(192) void prep_w2t(const float* __restrict__ W2, u16* __restrict__ W2t)
{
    const int n = blockIdx.x, k = threadIdx.x;
    W2t[n * 192 + k] = (n < 180 && k < 180) ? f2bf(W2[k * 180 + n]) : (u16)0;
}

__global__ __launch_bounds__(640) void prep_bias(const float* __restrict__ b1, const float* __restrict__ b2,
                                                 float* __restrict__ b1p, float* __restrict__ b2p)
{
    const int i = threadIdx.x;
    if (i < 384) b1p[i] = (i < 360) ? b1[i] : 0.0f;
    else { const int j = i - 384; b2p[j] = (j < 180) ? b2[j] : 0.0f; }
}

// per-channel sum/sumsq of x (65536 x 384). grid=256 x 384thr, 256 rows/block.
__global__ __launch_bounds__(384) void bn_stats(const u16* __restrict__ x, float* __restrict__ accum)
{
    const int ch = threadIdx.x;
    const long base = (long)blockIdx.x * 256 * 384;
    float s = 0.0f, s2 = 0.0f;
    for (int r = 0; r < 256; r++) {
        const float v = bf2f(x[base + (long)r * 384 + ch]);
        s += v; s2 += v * v;
    }
    atomicAdd(&accum[ch], s);
    atomicAdd(&accum[384 + ch], s2);
}

__global__ __launch_bounds__(384) void bn_finalize(const float* __restrict__ accum,
                                                   const float* __restrict__ bn_scale,
                                                   const float* __restrict__ bn_bias,
                                                   float* __restrict__ se, float* __restrict__ be)
{
    const int ch = threadIdx.x;
    const float mean = accum[ch] * (1.0f / 65536.0f);
    const float var = accum[384 + ch] * (1.0f / 65536.0f) - mean * mean;
    const float sc = (ch < 360) ? bn_scale[ch] : 0.0f;
    const float bi = (ch < 360) ? bn_bias[ch] : 0.0f;
    const float inv = rsqrtf(var + 1e-5f);
    se[ch] = sc * inv;
    be[ch] = bi - mean * sc * inv;
}

__global__ __launch_bounds__(256) void gather_qv(
    const u16* __restrict__ x, const float* __restrict__ se, const float* __restrict__ be,
    u16* __restrict__ q, u16* __restrict__ v,
    int g, int log2ws, int log2wc, int D, int Dpad)
{
    const int n = blockIdx.y;
    const int d = blockIdx.x * 256 + threadIdx.x;
    const long oq = (long)n * Dpad + d;
    if (d >= D) { q[oq] = 0; v[oq] = 0; return; }
    const int ws = 1 << log2ws, s = ws >> 1;
    const int cc = d % 60;
    const int pp = d / 60;
    const int dh = pp >> log2ws, dw = pp & (ws - 1);
    const int wcm = (1 << log2wc) - 1;
    const int wi = n & wcm;
    const int hi = (n >> log2wc) & wcm;
    const int b = n >> (2 * log2wc);
    const int row = ((hi << log2ws) + dh + s) & 127;
    const int col = ((wi << log2ws) + dw + s) & 127;
    const int ch = 120 * g + cc;
    const long src = ((long)((b << 7) + row) * 128 + col) * 384 + ch;
    const float xq = bf2f(x[src]);
    const float xv = bf2f(x[src + 60]);
    q[oq] = f2bf(se[ch] * xq + be[ch]);
    v[oq] = f2bf(se[ch + 60] * xv + be[ch + 60]);
}

__global__ __launch_bounds__(256) void transpose_bf16(
    const u16* __restrict__ src, u16* __restrict__ dst, int R, int Ccols)
{
    __shared__ u16 t[64][65];
    const int c0 = blockIdx.x * 64, r0 = blockIdx.y * 64;
    const int tc = threadIdx.x & 63;
    const int tr = threadIdx.x >> 6;
#pragma unroll
    for (int i = 0; i < 16; i++) {
        const int r = tr + i * 4;
        t[r][tc] = src[(long)(r0 + r) * Ccols + c0 + tc];
    }
    __syncthreads();
#pragma unroll
    for (int i = 0; i < 16; i++) {
        const int r = tr + i * 4;
        dst[(long)(c0 + r) * R + r0 + tc] = t[tc][r];
    }
}

// fused split-K reduce + row softmax. Reads nsplit partials of P (MN each),
// writes fp32 atn into S and bf16 copy into Sb. For nsplit==1, P may alias S.
template <int VPT>
__global__ __launch_bounds__(256) void softmax_rows(
    const float* __restrict__ P, int nsplit, long MN,
    float* __restrict__ S, u16* __restrict__ Sb)
{
    const int N = VPT * 256;
    const long base = (long)blockIdx.x * N;
    float v[VPT];
    float mx = -3.0e38f;
#pragma unroll
    for (int i = 0; i < VPT; i++) {
        const long idx = base + i * 256 + threadIdx.x;
        float val = P[idx];
        for (int z = 1; z < nsplit; z++) val += P[(long)z * MN + idx];
        v[i] = val; mx = fmaxf(mx, val);
    }
#pragma unroll
    for (int o = 32; o > 0; o >>= 1) mx = fmaxf(mx, __shfl_down(mx, o, 64));
    __shared__ float redm[4];
    if ((threadIdx.x & 63) == 0) redm[threadIdx.x >> 6] = mx;
    __syncthreads();
    mx = fmaxf(fmaxf(redm[0], redm[1]), fmaxf(redm[2], redm[3]));
    float s = 0.0f;
#pragma unroll
    for (int i = 0; i < VPT; i++) { v[i] = __expf(v[i] - mx); s += v[i]; }
#pragma unroll
    for (int o = 32; o > 0; o >>= 1) s += __shfl_down(s, o, 64);
    __shared__ float reds[4];
    if ((threadIdx.x & 63) == 0) reds[threadIdx.x >> 6] = s;
    __syncthreads();
    s = reds[0] + reds[1] + reds[2] + reds[3];
    const float inv = 1.0f / s;
#pragma unroll
    for (int i = 0; i < VPT; i++) {
        const float r = v[i] * inv;
        const long idx = base + i * 256 + threadIdx.x;
        S[idx] = r;
        Sb[idx] = f2bf(r);
    }
}

// fused split-K reduce + windowed scatter: P partials (nsplit x N x Dpad) -> Ysp (65536x192).
// grid = (ceil(Dpad/1024), N), 4 elems/thread (u16x4 store; 60 % 4 == 0 keeps runs intact).
__global__ __launch_bounds__(256) void reduce_scatter(
    const float* __restrict__ P, u16* __restrict__ Ysp, int nsplit, long MN,
    int g, int log2ws, int log2wc, int D, int Dpad)
{
    const int n = blockIdx.y;
    const int d = blockIdx.x * 1024 + threadIdx.x * 4;
    if (d >= D) return;
    const long i = (long)n * Dpad + d;
    f32x4 s = *(const f32x4*)(P + i);
    for (int z = 1; z < nsplit; z++) s += *(const f32x4*)(P + (long)z * MN + i);
    const int ws = 1 << log2ws, sh = ws >> 1;
    const int cc = d % 60;
    const int pp = d / 60;
    const int dh = pp >> log2ws, dw = pp & (ws - 1);
    const int wcm = (1 << log2wc) - 1;
    const int wi = n & wcm;
    const int hi = (n >> log2wc) & wcm;
    const int b = n >> (2 * log2wc);
    const int row = ((hi << log2ws) + dh + sh) & 127;
    const int col = ((wi << log2ws) + dw + sh) & 127;
    u16x4 o;
#pragma unroll
    for (int c = 0; c < 4; c++) o[c] = f2bf(s[c]);
    *(u16x4*)(Ysp + ((long)((b << 7) + row) * 128 + col) * 192 + 60 * g + cc) = o;
}

extern "C" void kernel_launch(void* const* d_in, const int* in_sizes, int n_in,
                              void* d_out, int out_size, void* d_ws, size_t ws_size,
                              hipStream_t stream)
{
    const float* in_x = (const float*)d_in[0];
    const float* w1  = (const float*)d_in[1];
    const float* b1  = (const float*)d_in[2];
    const float* bns = (const float*)d_in[3];
    const float* bnb = (const float*)d_in[4];
    const float* w2  = (const float*)d_in[5];
    const float* b2  = (const float*)d_in[6];
    float* out = (float*)d_out;

    char* w = (char*)d_ws;
    // region0 (33.55 MB): Abuf | qq partials (g1 33.5, g2 15.7) | PV partials (g1/g2 31.5)
    //                     | atnb for g0 (33.5). Lifetimes disjoint in stream order.
    u16* Abuf = (u16*)w;
    float* part0 = (float*)w;
    u16* atnb0 = (u16*)w;
    size_t off = 33554432;
    // x region (50.33 MB = 3 x 16.78): x until g0 gather, then g0 PV partials.
    u16* x = (u16*)(w + off);
    float* partx = (float*)(w + off);
    off += 50331648;
    u16* W1t = (u16*)(w + off);  off += 147456;
    u16* W2t = (u16*)(w + off);  off += 98304;
    float* b1p = (float*)(w + off);   off += 4096;
    float* b2p = (float*)(w + off);   off += 4096;
    float* accum = (float*)(w + off); off += 4096;
    float* se = (float*)(w + off);    off += 2048;
    float* be = (float*)(w + off);    off += 2048;
    u16* q  = (u16*)(w + off);   off += 8388608;
    u16* v  = (u16*)(w + off);   off += 8388608;   // doubles as atnb for g1/g2
    u16* vt = (u16*)(w + off);   off += 8388608;
    u16* Ysp = (u16*)(w + off);  off += 25165824;  // no memset: pad cols hit zero W2t rows

    hipMemsetAsync(accum, 0, 4096, stream);

    conv_input<<<65536, 192, 0, stream>>>(in_x, Abuf);
    prep_w1t<<<384, 192, 0, stream>>>(w1, W1t);
    prep_w2t<<<256, 192, 0, stream>>>(w2, W2t);
    prep_bias<<<1, 640, 0, stream>>>(b1, b2, b1p, b2p);

    // conv1: x = Abuf @ W1t^T + b1
    gemm_nt<u16><<<dim3(3, 512), 256, 0, stream>>>(Abuf, W1t, x, b1p, 192, 384, 384);
    bn_stats<<<256, 384, 0, stream>>>(x, accum);
    bn_finalize<<<1, 384, 0, stream>>>(accum, bns, bnb, se, be);

    const int  Ns[3]   = {4096, 1024, 256};
    const int  Ds[3]   = {960, 3840, 15360};
    const int  Dps[3]  = {1024, 3840, 15360};
    const int  l2ws[3] = {2, 3, 4};
    const int  l2wc[3] = {5, 4, 3};
    const int  nspl_qq[3] = {1, 8, 60};
    const int  nspl_pv[3] = {3, 2, 2};
    const int  kspl_pv[3] = {1376, 512, 128};
    const long atn_off[3] = {11796480L, 28573696L, 29622272L};

    // group order g2, g1, g0 (x dead before g0 PV partials reuse its region)
    const int order[3] = {2, 1, 0};
    for (int oi = 0; oi < 3; oi++) {
        const int g = order[oi];
        const int N = Ns[g], D = Ds[g], Dp = Dps[g];
        gather_qv<<<dim3(Dp / 256, N), 256, 0, stream>>>(x, se, be, q, v, g, l2ws[g], l2wc[g], D, Dp);
        transpose_bf16<<<dim3(Dp / 64, N / 64), 256, 0, stream>>>(v, vt, N, Dp);
        float* S = out + atn_off[g];
        const float* smP = S;   // softmax source (nsplit==1: in-place)
        if (nspl_qq[g] == 1) {
            gemm_nt<float><<<dim3(N / 128, N / 128), 256, 0, stream>>>(q, q, S, nullptr, Dp, N, N);
        } else {
            gemm_nt_splitk<<<dim3(N / 128, N / 128, nspl_qq[g]), 256, 0, stream>>>(
                q, q, part0, Dp, Dp / nspl_qq[g]);
            smP = part0;
        }
        u16* atnb = (g == 0) ? atnb0 : v;
        const long NN = (long)N * N;
        if (N == 4096)      softmax_rows<16><<<N, 256, 0, stream>>>(smP, nspl_qq[g], NN, S, atnb);
        else if (N == 1024) softmax_rows<4><<<N, 256, 0, stream>>>(smP, nspl_qq[g], NN, S, atnb);
        else                softmax_rows<1><<<N, 256, 0, stream>>>(smP, nspl_qq[g], NN, S, atnb);
        // Y = atn @ (v^T)^T via split-K, fused reduce+scatter into Ysp
        float* pvpart = (g == 0) ? partx : part0;
        const long MN = (long)N * Dp;
        gemm_nt_splitk<<<dim3(Dp / 128, N / 128, nspl_pv[g]), 256, 0, stream>>>(
            atnb, vt, pvpart, N, kspl_pv[g]);
        reduce_scatter<<<dim3((Dp + 1023) / 1024, N), 256, 0, stream>>>(
            pvpart, Ysp, nspl_pv[g], MN, g, l2ws[g], l2wc[g], D, Dp);
    }

    // conv2: out = Ysp @ W2t^T + b2
    gemm_nt<float><<<dim3(2, 512), 256, 0, stream>>>(Ysp, W2t, out, b2p, 192, 180, 180);
}

// Round 5
// 579.401 us; speedup vs baseline: 1.0479x; 1.0393x over previous
//
#include <hip/hip_runtime.h>

typedef unsigned short u16;
typedef __bf16 bf16x8 __attribute__((ext_vector_type(8)));
typedef float f32x4 __attribute__((ext_vector_type(4)));
typedef u16 u16x4 __attribute__((ext_vector_type(4)));
typedef u16 u16x8 __attribute__((ext_vector_type(8)));

__device__ __forceinline__ u16 f2bf(float v) {
    unsigned u = __float_as_uint(v);
    unsigned r = (u + 0x7fffu + ((u >> 16) & 1u)) >> 16;
    return (u16)r;
}
__device__ __forceinline__ float bf2f(u16 u) { return __uint_as_float(((unsigned)u) << 16); }

__device__ __forceinline__ void async_cp16(const u16* g, u16* l) {
    __builtin_amdgcn_global_load_lds((const __attribute__((address_space(1))) unsigned int*)g,
                                     (__attribute__((address_space(3))) unsigned int*)l, 16, 0, 0);
}

// C(MxNpad) = A(MxK) * B(Npad x K)^T (+bias[col]), store cols < n_store (LDS-coalesced epilogue).
template <typename OutT>
__global__ __launch_bounds__(256) void gemm_nt(
    const u16* __restrict__ A, const u16* __restrict__ B,
    OutT* __restrict__ C, const float* __restrict__ bias,
    int K, int ldc, int n_store)
{
    __shared__ char smem[16384];
    u16* As = (u16*)smem;
    u16* Bs = (u16*)(smem + 8192);
    const int tid = threadIdx.x;
    const int lane = tid & 63;
    const int wave = tid >> 6;
    const int wm = wave >> 1, wn = wave & 1;
    const long m0 = (long)blockIdx.y * 128;
    const long n0 = (long)blockIdx.x * 128;

    f32x4 acc[4][4] = {};

    const int lrow = tid >> 2;
    const int lk = (tid & 3) << 3;
    const u16* Ag = A + (m0 + lrow) * (long)K + lk;
    const u16* Bg = B + (n0 + lrow) * (long)K + lk;
    u16* Asl = As + tid * 8;
    u16* Bsl = Bs + tid * 8;
    const long K64 = (long)64 * K;

    for (int k0 = 0; k0 < K; k0 += 32) {
        async_cp16(Ag + k0, Asl);
        async_cp16(Ag + k0 + K64, Asl + 2048);
        async_cp16(Bg + k0, Bsl);
        async_cp16(Bg + k0 + K64, Bsl + 2048);
        __syncthreads();
        bf16x8 af[4], bg[4];
        const int ro = (lane & 15) * 32 + ((lane >> 4) << 3);
#pragma unroll
        for (int i = 0; i < 4; i++) af[i] = *(const bf16x8*)(As + (wm * 64 + i * 16) * 32 + ro);
#pragma unroll
        for (int j = 0; j < 4; j++) bg[j] = *(const bf16x8*)(Bs + (wn * 64 + j * 16) * 32 + ro);
#pragma unroll
        for (int i = 0; i < 4; i++)
#pragma unroll
            for (int j = 0; j < 4; j++)
                acc[i][j] = __builtin_amdgcn_mfma_f32_16x16x32_bf16(af[i], bg[j], acc[i][j], 0, 0, 0);
        __syncthreads();
    }

    float bv[4] = {0.0f, 0.0f, 0.0f, 0.0f};
    if (bias) {
#pragma unroll
        for (int j = 0; j < 4; j++) bv[j] = bias[n0 + wn * 64 + j * 16 + (lane & 15)];
    }

    if constexpr (sizeof(OutT) == 2) {
        u16* Cs = (u16*)smem;
        for (int c = 0; c < 2; c++) {
            __syncthreads();
            if (wm == c) {
#pragma unroll
                for (int i = 0; i < 4; i++)
#pragma unroll
                    for (int j = 0; j < 4; j++)
#pragma unroll
                        for (int r = 0; r < 4; r++) {
                            const int lr = i * 16 + ((lane >> 4) << 2) + r;
                            Cs[lr * 128 + wn * 64 + j * 16 + (lane & 15)] = f2bf(acc[i][j][r] + bv[j]);
                        }
            }
            __syncthreads();
            const int lr = tid >> 2;
            const int cg = (tid & 3) * 32;
            const long rowg = m0 + c * 64 + lr;
#pragma unroll
            for (int e = 0; e < 4; e++) {
                const int colg = cg + e * 8;
                if ((int)n0 + colg < n_store)
                    *(u16x8*)((u16*)C + rowg * (long)ldc + n0 + colg) = *(const u16x8*)(Cs + lr * 128 + colg);
            }
        }
    } else {
        float* Cs = (float*)smem;
        for (int c = 0; c < 4; c++) {
            __syncthreads();
            if (wm == (c >> 1)) {
#pragma unroll
                for (int ii = 0; ii < 2; ii++) {
                    const int i = (c & 1) * 2 + ii;
#pragma unroll
                    for (int j = 0; j < 4; j++)
#pragma unroll
                        for (int r = 0; r < 4; r++) {
                            const int lr = ii * 16 + ((lane >> 4) << 2) + r;
                            Cs[lr * 128 + wn * 64 + j * 16 + (lane & 15)] = acc[i][j][r] + bv[j];
                        }
                }
            }
            __syncthreads();
            const int lr = tid >> 3;
            const int cg = (tid & 7) * 16;
            const long rowg = m0 + c * 32 + lr;
#pragma unroll
            for (int e = 0; e < 4; e++) {
                const int colg = cg + e * 4;
                if ((int)n0 + colg < n_store)
                    *(f32x4*)((float*)C + rowg * (long)ldc + n0 + colg) = *(const f32x4*)(Cs + lr * 128 + colg);
            }
        }
    }
}

// conv1 fused: x(bf16 65536x384) = fp32 A(65536x180, logical K=192 zero-pad) @ W1t^T + b1
__global__ __launch_bounds__(256) void conv1_gemm(
    const float* __restrict__ A, const u16* __restrict__ B,
    u16* __restrict__ C, const float* __restrict__ bias)
{
    __shared__ char smem[16384];
    u16* As = (u16*)smem;
    u16* Bs = (u16*)(smem + 8192);
    const int tid = threadIdx.x;
    const int lane = tid & 63;
    const int wave = tid >> 6;
    const int wm = wave >> 1, wn = wave & 1;
    const long m0 = (long)blockIdx.y * 128;
    const long n0 = (long)blockIdx.x * 128;

    f32x4 acc[4][4] = {};

    const int lrow = tid >> 2;
    const int lk = (tid & 3) << 3;
    const float* Ar0 = A + (m0 + lrow) * 180L;
    const float* Ar1 = Ar0 + 64 * 180L;
    const u16* Bg = B + (n0 + lrow) * 192L + lk;
    u16* Asl = As + tid * 8;
    u16* Bsl = Bs + tid * 8;

#pragma unroll
    for (int k0 = 0; k0 < 192; k0 += 32) {
        const int gk = k0 + lk;
        // stage A rows (fp32 -> bf16) into LDS
        u16x8 oa, ob;
        if (gk + 8 <= 180) {
            f32x4 a0 = *(const f32x4*)(Ar0 + gk), a1 = *(const f32x4*)(Ar0 + gk + 4);
            f32x4 b0 = *(const f32x4*)(Ar1 + gk), b1 = *(const f32x4*)(Ar1 + gk + 4);
#pragma unroll
            for (int c = 0; c < 4; c++) {
                oa[c] = f2bf(a0[c]); oa[4 + c] = f2bf(a1[c]);
                ob[c] = f2bf(b0[c]); ob[4 + c] = f2bf(b1[c]);
            }
            // note: oa holds Ar0[gk..gk+4)+Ar0[gk+4..gk+8)? fixed below
        }
        if (gk + 8 <= 180) {
            f32x4 a0 = *(const f32x4*)(Ar0 + gk), a1 = *(const f32x4*)(Ar0 + gk + 4);
            f32x4 b0 = *(const f32x4*)(Ar1 + gk), b1 = *(const f32x4*)(Ar1 + gk + 4);
#pragma unroll
            for (int c = 0; c < 4; c++) {
                oa[c] = f2bf(a0[c]); oa[4 + c] = f2bf(a1[c]);
                ob[c] = f2bf(b0[c]); ob[4 + c] = f2bf(b1[c]);
            }
        } else if (gk < 180) {   // gk == 176: 4 valid + 4 pad
            f32x4 a0 = *(const f32x4*)(Ar0 + gk);
            f32x4 b0 = *(const f32x4*)(Ar1 + gk);
#pragma unroll
            for (int c = 0; c < 4; c++) {
                oa[c] = f2bf(a0[c]); oa[4 + c] = 0;
                ob[c] = f2bf(b0[c]); ob[4 + c] = 0;
            }
        } else {
#pragma unroll
            for (int c = 0; c < 8; c++) { oa[c] = 0; ob[c] = 0; }
        }
        *(u16x8*)Asl = oa;
        *(u16x8*)(Asl + 2048) = ob;
        async_cp16(Bg + k0, Bsl);
        async_cp16(Bg + k0 + 64 * 192, Bsl + 2048);
        __syncthreads();
        bf16x8 af[4], bg[4];
        const int ro = (lane & 15) * 32 + ((lane >> 4) << 3);
#pragma unroll
        for (int i = 0; i < 4; i++) af[i] = *(const bf16x8*)(As + (wm * 64 + i * 16) * 32 + ro);
#pragma unroll
        for (int j = 0; j < 4; j++) bg[j] = *(const bf16x8*)(Bs + (wn * 64 + j * 16) * 32 + ro);
#pragma unroll
        for (int i = 0; i < 4; i++)
#pragma unroll
            for (int j = 0; j < 4; j++)
                acc[i][j] = __builtin_amdgcn_mfma_f32_16x16x32_bf16(af[i], bg[j], acc[i][j], 0, 0, 0);
        __syncthreads();
    }

    float bv[4];
#pragma unroll
    for (int j = 0; j < 4; j++) bv[j] = bias[n0 + wn * 64 + j * 16 + (lane & 15)];

    u16* Cs = (u16*)smem;
    for (int c = 0; c < 2; c++) {
        __syncthreads();
        if (wm == c) {
#pragma unroll
            for (int i = 0; i < 4; i++)
#pragma unroll
                for (int j = 0; j < 4; j++)
#pragma unroll
                    for (int r = 0; r < 4; r++) {
                        const int lr = i * 16 + ((lane >> 4) << 2) + r;
                        Cs[lr * 128 + wn * 64 + j * 16 + (lane & 15)] = f2bf(acc[i][j][r] + bv[j]);
                    }
        }
        __syncthreads();
        const int lr = tid >> 2;
        const int cg = (tid & 3) * 32;
        const long rowg = m0 + c * 64 + lr;
#pragma unroll
        for (int e = 0; e < 4; e++) {
            const int colg = cg + e * 8;
            *(u16x8*)(C + rowg * 384L + n0 + colg) = *(const u16x8*)(Cs + lr * 128 + colg);
        }
    }
}

// Split-K: P[z][M][Npad] fp32 partials, coalesced epilogue. grid=(Npad/128, M/128, nsplit).
__global__ __launch_bounds__(256) void gemm_nt_splitk(
    const u16* __restrict__ A, const u16* __restrict__ B,
    float* __restrict__ P, int K, int Ksplit)
{
    __shared__ char smem[16384];
    u16* As = (u16*)smem;
    u16* Bs = (u16*)(smem + 8192);
    const int tid = threadIdx.x;
    const int lane = tid & 63;
    const int wave = tid >> 6;
    const int wm = wave >> 1, wn = wave & 1;
    const long m0 = (long)blockIdx.y * 128;
    const long n0 = (long)blockIdx.x * 128;
    const int kbeg = blockIdx.z * Ksplit;
    const int kend = min(kbeg + Ksplit, K);
    const int Npad = gridDim.x * 128;
    const long M = (long)gridDim.y * 128;

    f32x4 acc[4][4] = {};

    const int lrow = tid >> 2;
    const int lk = (tid & 3) << 3;
    const u16* Ag = A + (m0 + lrow) * (long)K + lk;
    const u16* Bg = B + (n0 + lrow) * (long)K + lk;
    u16* Asl = As + tid * 8;
    u16* Bsl = Bs + tid * 8;
    const long K64 = (long)64 * K;

    for (int k0 = kbeg; k0 < kend; k0 += 32) {
        async_cp16(Ag + k0, Asl);
        async_cp16(Ag + k0 + K64, Asl + 2048);
        async_cp16(Bg + k0, Bsl);
        async_cp16(Bg + k0 + K64, Bsl + 2048);
        __syncthreads();
        bf16x8 af[4], bg[4];
        const int ro = (lane & 15) * 32 + ((lane >> 4) << 3);
#pragma unroll
        for (int i = 0; i < 4; i++) af[i] = *(const bf16x8*)(As + (wm * 64 + i * 16) * 32 + ro);
#pragma unroll
        for (int j = 0; j < 4; j++) bg[j] = *(const bf16x8*)(Bs + (wn * 64 + j * 16) * 32 + ro);
#pragma unroll
        for (int i = 0; i < 4; i++)
#pragma unroll
            for (int j = 0; j < 4; j++)
                acc[i][j] = __builtin_amdgcn_mfma_f32_16x16x32_bf16(af[i], bg[j], acc[i][j], 0, 0, 0);
        __syncthreads();
    }

    float* Pz = P + (long)blockIdx.z * M * Npad;
    float* Cs = (float*)smem;
    for (int c = 0; c < 4; c++) {
        __syncthreads();
        if (wm == (c >> 1)) {
#pragma unroll
            for (int ii = 0; ii < 2; ii++) {
                const int i = (c & 1) * 2 + ii;
#pragma unroll
                for (int j = 0; j < 4; j++)
#pragma unroll
                    for (int r = 0; r < 4; r++) {
                        const int lr = ii * 16 + ((lane >> 4) << 2) + r;
                        Cs[lr * 128 + wn * 64 + j * 16 + (lane & 15)] = acc[i][j][r];
                    }
            }
        }
        __syncthreads();
        const int lr = tid >> 3;
        const int cg = (tid & 7) * 16;
        const long rowg = m0 + c * 32 + lr;
#pragma unroll
        for (int e = 0; e < 4; e++) {
            const int colg = cg + e * 4;
            *(f32x4*)(Pz + rowg * (long)Npad + n0 + colg) = *(const f32x4*)(Cs + lr * 128 + colg);
        }
    }
}

// single prep dispatch: W1t, W2t, padded biases, accum zero.
__global__ __launch_bounds__(192) void prep_all(
    const float* __restrict__ W1, const float* __restrict__ W2,
    const float* __restrict__ b1, const float* __restrict__ b2,
    u16* __restrict__ W1t, u16* __restrict__ W2t,
    float* __restrict__ b1p, float* __restrict__ b2p, float* __restrict__ accum)
{
    const int bid = blockIdx.x;
    const int t = threadIdx.x;
    if (bid < 384) {
        W1t[bid * 192 + t] = (bid < 360 && t < 180) ? f2bf(W1[t * 360 + bid]) : (u16)0;
    } else if (bid < 640) {
        const int n = bid - 384;
        W2t[n * 192 + t] = (n < 180 && t < 180) ? f2bf(W2[t * 180 + n]) : (u16)0;
    } else {
#pragma unroll
        for (int j = 0; j < 4; j++) {
            const int i = t + 192 * j;
            if (i < 384) b1p[i] = (i < 360) ? b1[i] : 0.0f;
            else if (i < 640) { const int k = i - 384; b2p[k] = (k < 180) ? b2[k] : 0.0f; }
            if (i < 768) accum[i] = 0.0f;
        }
    }
}

// per-channel sum/sumsq of x (65536 x 384). grid=256 x 384thr.
__global__ __launch_bounds__(384) void bn_stats(const u16* __restrict__ x, float* __restrict__ accum)
{
    const int ch = threadIdx.x;
    const long base = (long)blockIdx.x * 256 * 384;
    float s = 0.0f, s2 = 0.0f;
    for (int r = 0; r < 256; r++) {
        const float v = bf2f(x[base + (long)r * 384 + ch]);
        s += v; s2 += v * v;
    }
    atomicAdd(&accum[ch], s);
    atomicAdd(&accum[384 + ch], s2);
}

__global__ __launch_bounds__(384) void bn_finalize(const float* __restrict__ accum,
                                                   const float* __restrict__ bn_scale,
                                                   const float* __restrict__ bn_bias,
                                                   float* __restrict__ se, float* __restrict__ be)
{
    const int ch = threadIdx.x;
    const float mean = accum[ch] * (1.0f / 65536.0f);
    const float var = accum[384 + ch] * (1.0f / 65536.0f) - mean * mean;
    const float sc = (ch < 360) ? bn_scale[ch] : 0.0f;
    const float bi = (ch < 360) ? bn_bias[ch] : 0.0f;
    const float inv = rsqrtf(var + 1e-5f);
    se[ch] = sc * inv;
    be[ch] = bi - mean * sc * inv;
}

// fused windowed gather + BN + transpose: x -> q (N x Dp) and vt (Dp x N).
// grid = (Dp/64, N/64), block 256. For d >= D: q forced 0; vt rows hold finite
// garbage (outputs for those cols are never scattered).
__global__ __launch_bounds__(256) void gather_qv_t(
    const u16* __restrict__ x, const float* __restrict__ se, const float* __restrict__ be,
    u16* __restrict__ q, u16* __restrict__ vt,
    int g, int log2ws, int log2wc, int D, int Dpad, int N)
{
    __shared__ u16 t[64][65];
    const int d0 = blockIdx.x * 64;
    const int n0 = blockIdx.y * 64;
    const int tc = threadIdx.x & 63;
    const int tr = threadIdx.x >> 6;

    const int d = d0 + tc;
    const int ws = 1 << log2ws, sh = ws >> 1;
    const int cc = d % 60;
    const int pp = d / 60;
    const int dh = pp >> log2ws, dw = pp & (ws - 1);
    const int wcm = (1 << log2wc) - 1;
    const int ch = 120 * g + cc;
    const float seq = se[ch], beq = be[ch];
    const float sev = se[ch + 60], bev = be[ch + 60];
    const bool valid = d < D;

#pragma unroll 4
    for (int i = 0; i < 16; i++) {
        const int n = n0 + i * 4 + tr;
        const int wi = n & wcm;
        const int hi = (n >> log2wc) & wcm;
        const int b = n >> (2 * log2wc);
        const int row = ((hi << log2ws) + dh + sh) & 127;
        const int col = ((wi << log2ws) + dw + sh) & 127;
        const long src = ((long)((b << 7) + row) * 128 + col) * 384 + ch;
        const float xq = bf2f(x[src]);
        const float xv = bf2f(x[src + 60]);
        q[(long)n * Dpad + d] = valid ? f2bf(seq * xq + beq) : (u16)0;
        t[tc][i * 4 + tr] = f2bf(sev * xv + bev);
    }
    __syncthreads();
#pragma unroll 4
    for (int i = 0; i < 16; i++) {
        const int dd = i * 4 + tr;
        vt[(long)(d0 + dd) * N + n0 + tc] = t[dd][tc];
    }
}

// fused split-K reduce + row softmax.
template <int VPT>
__global__ __launch_bounds__(256) void softmax_rows(
    const float* __restrict__ P, int nsplit, long MN,
    float* __restrict__ S, u16* __restrict__ Sb)
{
    const int N = VPT * 256;
    const long base = (long)blockIdx.x * N;
    float v[VPT];
    float mx = -3.0e38f;
#pragma unroll
    for (int i = 0; i < VPT; i++) {
        const long idx = base + i * 256 + threadIdx.x;
        float val = P[idx];
        for (int z = 1; z < nsplit; z++) val += P[(long)z * MN + idx];
        v[i] = val; mx = fmaxf(mx, val);
    }
#pragma unroll
    for (int o = 32; o > 0; o >>= 1) mx = fmaxf(mx, __shfl_down(mx, o, 64));
    __shared__ float redm[4];
    if ((threadIdx.x & 63) == 0) redm[threadIdx.x >> 6] = mx;
    __syncthreads();
    mx = fmaxf(fmaxf(redm[0], redm[1]), fmaxf(redm[2], redm[3]));
    float s = 0.0f;
#pragma unroll
    for (int i = 0; i < VPT; i++) { v[i] = __expf(v[i] - mx); s += v[i]; }
#pragma unroll
    for (int o = 32; o > 0; o >>= 1) s += __shfl_down(s, o, 64);
    __shared__ float reds[4];
    if ((threadIdx.x & 63) == 0) reds[threadIdx.x >> 6] = s;
    __syncthreads();
    s = reds[0] + reds[1] + reds[2] + reds[3];
    const float inv = 1.0f / s;
#pragma unroll
    for (int i = 0; i < VPT; i++) {
        const float r = v[i] * inv;
        const long idx = base + i * 256 + threadIdx.x;
        S[idx] = r;
        Sb[idx] = f2bf(r);
    }
}

// fused split-K reduce + windowed scatter into Ysp (65536x192).
__global__ __launch_bounds__(256) void reduce_scatter(
    const float* __restrict__ P, u16* __restrict__ Ysp, int nsplit, long MN,
    int g, int log2ws, int log2wc, int D, int Dpad)
{
    const int n = blockIdx.y;
    const int d = blockIdx.x * 1024 + threadIdx.x * 4;
    if (d >= D) return;
    const long i = (long)n * Dpad + d;
    f32x4 s = *(const f32x4*)(P + i);
    for (int z = 1; z < nsplit; z++) s += *(const f32x4*)(P + (long)z * MN + i);
    const int ws = 1 << log2ws, sh = ws >> 1;
    const int cc = d % 60;
    const int pp = d / 60;
    const int dh = pp >> log2ws, dw = pp & (ws - 1);
    const int wcm = (1 << log2wc) - 1;
    const int wi = n & wcm;
    const int hi = (n >> log2wc) & wcm;
    const int b = n >> (2 * log2wc);
    const int row = ((hi << log2ws) + dh + sh) & 127;
    const int col = ((wi << log2ws) + dw + sh) & 127;
    u16x4 o;
#pragma unroll
    for (int c = 0; c < 4; c++) o[c] = f2bf(s[c]);
    *(u16x4*)(Ysp + ((long)((b << 7) + row) * 128 + col) * 192 + 60 * g + cc) = o;
}

extern "C" void kernel_launch(void* const* d_in, const int* in_sizes, int n_in,
                              void* d_out, int out_size, void* d_ws, size_t ws_size,
                              hipStream_t stream)
{
    const float* in_x = (const float*)d_in[0];
    const float* w1  = (const float*)d_in[1];
    const float* b1  = (const float*)d_in[2];
    const float* bns = (const float*)d_in[3];
    const float* bnb = (const float*)d_in[4];
    const float* w2  = (const float*)d_in[5];
    const float* b2  = (const float*)d_in[6];
    float* out = (float*)d_out;

    char* w = (char*)d_ws;
    // region0 (33.55 MB): qq partials (g1 33.5, g2 15.7) | PV partials (g1/g2 31.5)
    //                     | atnb for g0 (33.5). Lifetimes disjoint in stream order.
    float* part0 = (float*)w;
    u16* atnb0 = (u16*)w;
    size_t off = 33554432;
    // x region (50.33 MB = 3 x 16.78): x until g0 gather, then g0 PV partials.
    u16* x = (u16*)(w + off);
    float* partx = (float*)(w + off);
    off += 50331648;
    u16* W1t = (u16*)(w + off);  off += 147456;
    u16* W2t = (u16*)(w + off);  off += 98304;
    float* b1p = (float*)(w + off);   off += 4096;
    float* b2p = (float*)(w + off);   off += 4096;
    float* accum = (float*)(w + off); off += 4096;
    float* se = (float*)(w + off);    off += 2048;
    float* be = (float*)(w + off);    off += 2048;
    u16* q  = (u16*)(w + off);    off += 8388608;
    u16* atnb12 = (u16*)(w + off); off += 8388608;  // bf16 atn for g1/g2
    u16* vt = (u16*)(w + off);    off += 8388608;
    u16* Ysp = (u16*)(w + off);   off += 25165824;  // no memset: pad cols hit zero W2t rows

    prep_all<<<641, 192, 0, stream>>>(w1, w2, b1, b2, W1t, W2t, b1p, b2p, accum);

    // conv1 (fused fp32->bf16 A staging): x = A @ W1t^T + b1
    conv1_gemm<<<dim3(3, 512), 256, 0, stream>>>(in_x, W1t, x, b1p);
    bn_stats<<<256, 384, 0, stream>>>(x, accum);
    bn_finalize<<<1, 384, 0, stream>>>(accum, bns, bnb, se, be);

    const int  Ns[3]   = {4096, 1024, 256};
    const int  Ds[3]   = {960, 3840, 15360};
    const int  Dps[3]  = {1024, 3840, 15360};
    const int  l2ws[3] = {2, 3, 4};
    const int  l2wc[3] = {5, 4, 3};
    const int  nspl_qq[3] = {1, 8, 60};
    const int  nspl_pv[3] = {3, 2, 2};
    const int  kspl_pv[3] = {1376, 512, 128};
    const long atn_off[3] = {11796480L, 28573696L, 29622272L};

    // group order g2, g1, g0 (x dead before g0 PV partials reuse its region)
    const int order[3] = {2, 1, 0};
    for (int oi = 0; oi < 3; oi++) {
        const int g = order[oi];
        const int N = Ns[g], D = Ds[g], Dp = Dps[g];
        gather_qv_t<<<dim3(Dp / 64, N / 64), 256, 0, stream>>>(
            x, se, be, q, vt, g, l2ws[g], l2wc[g], D, Dp, N);
        float* S = out + atn_off[g];
        const float* smP = S;
        if (nspl_qq[g] == 1) {
            gemm_nt<float><<<dim3(N / 128, N / 128), 256, 0, stream>>>(q, q, S, nullptr, Dp, N, N);
        } else {
            gemm_nt_splitk<<<dim3(N / 128, N / 128, nspl_qq[g]), 256, 0, stream>>>(
                q, q, part0, Dp, Dp / nspl_qq[g]);
            smP = part0;
        }
        u16* atnb = (g == 0) ? atnb0 : atnb12;
        const long NN = (long)N * N;
        if (N == 4096)      softmax_rows<16><<<N, 256, 0, stream>>>(smP, nspl_qq[g], NN, S, atnb);
        else if (N == 1024) softmax_rows<4><<<N, 256, 0, stream>>>(smP, nspl_qq[g], NN, S, atnb);
        else                softmax_rows<1><<<N, 256, 0, stream>>>(smP, nspl_qq[g], NN, S, atnb);
        // Y = atn @ (v^T)^T via split-K, fused reduce+scatter into Ysp
        float* pvpart = (g == 0) ? partx : part0;
        const long MN = (long)N * Dp;
        gemm_nt_splitk<<<dim3(Dp / 128, N / 128, nspl_pv[g]), 256, 0, stream>>>(
            atnb, vt, pvpart, N, kspl_pv[g]);
        reduce_scatter<<<dim3((Dp + 1023) / 1024, N), 256, 0, stream>>>(
            pvpart, Ysp, nspl_pv[g], MN, g, l2ws[g], l2wc[g], D, Dp);
    }

    // conv2: out = Ysp @ W2t^T + b2
    gemm_nt<float><<<dim3(2, 512), 256, 0, stream>>>(Ysp, W2t, out, b2p, 192, 180, 180);
}

// Round 7
// 485.389 us; speedup vs baseline: 1.2509x; 1.1937x over previous
//
#include <hip/hip_runtime.h>

typedef unsigned short u16;
typedef __bf16 bf16x8 __attribute__((ext_vector_type(8)));
typedef float f32x4 __attribute__((ext_vector_type(4)));
typedef u16 u16x4 __attribute__((ext_vector_type(4)));
typedef u16 u16x8 __attribute__((ext_vector_type(8)));

__device__ __forceinline__ u16 f2bf(float v) {
    unsigned u = __float_as_uint(v);
    unsigned r = (u + 0x7fffu + ((u >> 16) & 1u)) >> 16;
    return (u16)r;
}
__device__ __forceinline__ float bf2f(u16 u) { return __uint_as_float(((unsigned)u) << 16); }

__device__ __forceinline__ void async_cp16(const u16* g, u16* l) {
    __builtin_amdgcn_global_load_lds((const __attribute__((address_space(1))) unsigned int*)g,
                                     (__attribute__((address_space(3))) unsigned int*)l, 16, 0, 0);
}

// ---------------- conv2 GEMM (fp32 out, bias, col guard) ----------------
__global__ __launch_bounds__(256) void gemm_f32(
    const u16* __restrict__ A, const u16* __restrict__ B,
    float* __restrict__ C, const float* __restrict__ bias,
    int K, int ldc, int n_store)
{
    __shared__ char smem[16384];
    u16* As = (u16*)smem;
    u16* Bs = (u16*)(smem + 8192);
    const int tid = threadIdx.x;
    const int lane = tid & 63;
    const int wave = tid >> 6;
    const int wm = wave >> 1, wn = wave & 1;
    const long m0 = (long)blockIdx.y * 128;
    const long n0 = (long)blockIdx.x * 128;

    f32x4 acc[4][4] = {};
    const int lrow = tid >> 2;
    const int lk = (tid & 3) << 3;
    const u16* Ag = A + (m0 + lrow) * (long)K + lk;
    const u16* Bg = B + (n0 + lrow) * (long)K + lk;
    u16* Asl = As + tid * 8;
    u16* Bsl = Bs + tid * 8;
    const long K64 = (long)64 * K;

    for (int k0 = 0; k0 < K; k0 += 32) {
        async_cp16(Ag + k0, Asl);
        async_cp16(Ag + k0 + K64, Asl + 2048);
        async_cp16(Bg + k0, Bsl);
        async_cp16(Bg + k0 + K64, Bsl + 2048);
        __syncthreads();
        bf16x8 af[4], bg[4];
        const int ro = (lane & 15) * 32 + ((lane >> 4) << 3);
#pragma unroll
        for (int i = 0; i < 4; i++) af[i] = *(const bf16x8*)(As + (wm * 64 + i * 16) * 32 + ro);
#pragma unroll
        for (int j = 0; j < 4; j++) bg[j] = *(const bf16x8*)(Bs + (wn * 64 + j * 16) * 32 + ro);
#pragma unroll
        for (int i = 0; i < 4; i++)
#pragma unroll
            for (int j = 0; j < 4; j++)
                acc[i][j] = __builtin_amdgcn_mfma_f32_16x16x32_bf16(af[i], bg[j], acc[i][j], 0, 0, 0);
        __syncthreads();
    }

    float bv[4];
#pragma unroll
    for (int j = 0; j < 4; j++) bv[j] = bias[n0 + wn * 64 + j * 16 + (lane & 15)];

    float* Cs = (float*)smem;
    for (int c = 0; c < 4; c++) {
        __syncthreads();
        if (wm == (c >> 1)) {
#pragma unroll
            for (int ii = 0; ii < 2; ii++) {
                const int i = (c & 1) * 2 + ii;
#pragma unroll
                for (int j = 0; j < 4; j++)
#pragma unroll
                    for (int r = 0; r < 4; r++) {
                        const int lr = ii * 16 + ((lane >> 4) << 2) + r;
                        Cs[lr * 128 + wn * 64 + j * 16 + (lane & 15)] = acc[i][j][r] + bv[j];
                    }
            }
        }
        __syncthreads();
        const int lr = tid >> 3;
        const int cg = (tid & 7) * 16;
        const long rowg = m0 + c * 32 + lr;
#pragma unroll
        for (int e = 0; e < 4; e++) {
            const int colg = cg + e * 4;
            if ((int)n0 + colg < n_store)
                *(f32x4*)(C + rowg * (long)ldc + n0 + colg) = *(const f32x4*)(Cs + lr * 128 + colg);
        }
    }
}

// ---------------- conv1 fused: x = fp32 A(65536x180, K pad 192) @ W1t^T + b1 ----------------
__global__ __launch_bounds__(256) void conv1_gemm(
    const float* __restrict__ A, const u16* __restrict__ B,
    u16* __restrict__ C, const float* __restrict__ bias)
{
    __shared__ char smem[16384];
    u16* As = (u16*)smem;
    u16* Bs = (u16*)(smem + 8192);
    const int tid = threadIdx.x;
    const int lane = tid & 63;
    const int wave = tid >> 6;
    const int wm = wave >> 1, wn = wave & 1;
    const long m0 = (long)blockIdx.y * 128;
    const long n0 = (long)blockIdx.x * 128;

    f32x4 acc[4][4] = {};
    const int lrow = tid >> 2;
    const int lk = (tid & 3) << 3;
    const float* Ar0 = A + (m0 + lrow) * 180L;
    const float* Ar1 = Ar0 + 64 * 180L;
    const u16* Bg = B + (n0 + lrow) * 192L + lk;
    u16* Asl = As + tid * 8;
    u16* Bsl = Bs + tid * 8;

#pragma unroll
    for (int k0 = 0; k0 < 192; k0 += 32) {
        const int gk = k0 + lk;
        u16x8 oa, ob;
        if (gk + 8 <= 180) {
            f32x4 a0 = *(const f32x4*)(Ar0 + gk), a1 = *(const f32x4*)(Ar0 + gk + 4);
            f32x4 b0 = *(const f32x4*)(Ar1 + gk), b1 = *(const f32x4*)(Ar1 + gk + 4);
#pragma unroll
            for (int c = 0; c < 4; c++) {
                oa[c] = f2bf(a0[c]); oa[4 + c] = f2bf(a1[c]);
                ob[c] = f2bf(b0[c]); ob[4 + c] = f2bf(b1[c]);
            }
        } else if (gk < 180) {   // gk == 176
            f32x4 a0 = *(const f32x4*)(Ar0 + gk);
            f32x4 b0 = *(const f32x4*)(Ar1 + gk);
#pragma unroll
            for (int c = 0; c < 4; c++) {
                oa[c] = f2bf(a0[c]); oa[4 + c] = 0;
                ob[c] = f2bf(b0[c]); ob[4 + c] = 0;
            }
        } else {
#pragma unroll
            for (int c = 0; c < 8; c++) { oa[c] = 0; ob[c] = 0; }
        }
        *(u16x8*)Asl = oa;
        *(u16x8*)(Asl + 2048) = ob;
        async_cp16(Bg + k0, Bsl);
        async_cp16(Bg + k0 + 64 * 192, Bsl + 2048);
        __syncthreads();
        bf16x8 af[4], bg[4];
        const int ro = (lane & 15) * 32 + ((lane >> 4) << 3);
#pragma unroll
        for (int i = 0; i < 4; i++) af[i] = *(const bf16x8*)(As + (wm * 64 + i * 16) * 32 + ro);
#pragma unroll
        for (int j = 0; j < 4; j++) bg[j] = *(const bf16x8*)(Bs + (wn * 64 + j * 16) * 32 + ro);
#pragma unroll
        for (int i = 0; i < 4; i++)
#pragma unroll
            for (int j = 0; j < 4; j++)
                acc[i][j] = __builtin_amdgcn_mfma_f32_16x16x32_bf16(af[i], bg[j], acc[i][j], 0, 0, 0);
        __syncthreads();
    }

    float bv[4];
#pragma unroll
    for (int j = 0; j < 4; j++) bv[j] = bias[n0 + wn * 64 + j * 16 + (lane & 15)];

    u16* Cs = (u16*)smem;
    for (int c = 0; c < 2; c++) {
        __syncthreads();
        if (wm == c) {
#pragma unroll
            for (int i = 0; i < 4; i++)
#pragma unroll
                for (int j = 0; j < 4; j++)
#pragma unroll
                    for (int r = 0; r < 4; r++) {
                        const int lr = i * 16 + ((lane >> 4) << 2) + r;
                        Cs[lr * 128 + wn * 64 + j * 16 + (lane & 15)] = f2bf(acc[i][j][r] + bv[j]);
                    }
        }
        __syncthreads();
        const int lr = tid >> 2;
        const int cg = (tid & 3) * 32;
        const long rowg = m0 + c * 64 + lr;
#pragma unroll
        for (int e = 0; e < 4; e++) {
            const int colg = cg + e * 8;
            *(u16x8*)(C + rowg * 384L + n0 + colg) = *(const u16x8*)(Cs + lr * 128 + colg);
        }
    }
}

// ---------------- grouped qq^T: all 3 groups + split-K in ONE dispatch ----------------
// blocks: [0,1024) g0 32x32 z=1 | [1024,1536) g1 8x8 z=8 | [1536,1776) g2 2x2 z=60
__global__ __launch_bounds__(256) void qq_all(
    const u16* __restrict__ q0, const u16* __restrict__ q1, const u16* __restrict__ q2,
    float* __restrict__ S0, float* __restrict__ pG1, float* __restrict__ pG2)
{
    __shared__ char smem[16384];
    u16* As = (u16*)smem;
    u16* Bs = (u16*)(smem + 8192);
    const int bid = blockIdx.x;
    int seg, local;
    if (bid < 1024) { seg = 0; local = bid; }
    else if (bid < 1536) { seg = 1; local = bid - 1024; }
    else { seg = 2; local = bid - 1536; }
    const int tX = seg == 0 ? 32 : (seg == 1 ? 8 : 2);
    const int tt = tX * tX;
    const int K = seg == 0 ? 1024 : (seg == 1 ? 3840 : 15360);
    const int Ksplit = seg == 0 ? 1024 : (seg == 1 ? 480 : 256);
    const int N = seg == 0 ? 4096 : (seg == 1 ? 1024 : 256);
    const u16* A = seg == 0 ? q0 : (seg == 1 ? q1 : q2);
    float* outP = seg == 0 ? S0 : (seg == 1 ? pG1 : pG2);
    const int z = local / tt;
    const int rem = local - z * tt;
    const int bx = rem % tX;
    const int by = rem / tX;

    const int tid = threadIdx.x;
    const int lane = tid & 63;
    const int wave = tid >> 6;
    const int wm = wave >> 1, wn = wave & 1;
    const long m0 = (long)by * 128;
    const long n0 = (long)bx * 128;
    const int kbeg = z * Ksplit;

    f32x4 acc[4][4] = {};
    const int lrow = tid >> 2;
    const int lk = (tid & 3) << 3;
    const u16* Ag = A + (m0 + lrow) * (long)K + lk;
    const u16* Bg = A + (n0 + lrow) * (long)K + lk;
    u16* Asl = As + tid * 8;
    u16* Bsl = Bs + tid * 8;
    const long K64 = (long)64 * K;

    for (int k0 = kbeg; k0 < kbeg + Ksplit; k0 += 32) {
        async_cp16(Ag + k0, Asl);
        async_cp16(Ag + k0 + K64, Asl + 2048);
        async_cp16(Bg + k0, Bsl);
        async_cp16(Bg + k0 + K64, Bsl + 2048);
        __syncthreads();
        bf16x8 af[4], bg[4];
        const int ro = (lane & 15) * 32 + ((lane >> 4) << 3);
#pragma unroll
        for (int i = 0; i < 4; i++) af[i] = *(const bf16x8*)(As + (wm * 64 + i * 16) * 32 + ro);
#pragma unroll
        for (int j = 0; j < 4; j++) bg[j] = *(const bf16x8*)(Bs + (wn * 64 + j * 16) * 32 + ro);
#pragma unroll
        for (int i = 0; i < 4; i++)
#pragma unroll
            for (int j = 0; j < 4; j++)
                acc[i][j] = __builtin_amdgcn_mfma_f32_16x16x32_bf16(af[i], bg[j], acc[i][j], 0, 0, 0);
        __syncthreads();
    }

    float* Pz = outP + (long)z * N * N;
    float* Cs = (float*)smem;
    for (int c = 0; c < 4; c++) {
        __syncthreads();
        if (wm == (c >> 1)) {
#pragma unroll
            for (int ii = 0; ii < 2; ii++) {
                const int i = (c & 1) * 2 + ii;
#pragma unroll
                for (int j = 0; j < 4; j++)
#pragma unroll
                    for (int r = 0; r < 4; r++) {
                        const int lr = ii * 16 + ((lane >> 4) << 2) + r;
                        Cs[lr * 128 + wn * 64 + j * 16 + (lane & 15)] = acc[i][j][r];
                    }
            }
        }
        __syncthreads();
        const int lr = tid >> 3;
        const int cg = (tid & 7) * 16;
        const long rowg = m0 + c * 32 + lr;
#pragma unroll
        for (int e = 0; e < 4; e++) {
            const int colg = cg + e * 4;
            *(f32x4*)(Pz + rowg * (long)N + n0 + colg) = *(const f32x4*)(Cs + lr * 128 + colg);
        }
    }
}

// ---------------- grouped PV: Y = atn @ vt^T with scatter-to-Ysp epilogue ----------------
// blocks: [0,256) g0 8x32 | [256,496) g1 30x8 | [496,736) g2 120x2
__global__ __launch_bounds__(256) void pv_all(
    const u16* __restrict__ a0, const u16* __restrict__ a1, const u16* __restrict__ a2,
    const u16* __restrict__ vt0, const u16* __restrict__ vt1, const u16* __restrict__ vt2,
    u16* __restrict__ Ysp)
{
    __shared__ char smem[16384];
    u16* As = (u16*)smem;
    u16* Bs = (u16*)(smem + 8192);
    const int bid = blockIdx.x;
    int seg, local;
    if (bid < 256) { seg = 0; local = bid; }
    else if (bid < 496) { seg = 1; local = bid - 256; }
    else { seg = 2; local = bid - 496; }
    const int tX = seg == 0 ? 8 : (seg == 1 ? 30 : 120);
    const int K = seg == 0 ? 4096 : (seg == 1 ? 1024 : 256);
    const int D = seg == 0 ? 960 : (seg == 1 ? 3840 : 15360);
    const int l2ws = 2 + seg;
    const int l2wc = 5 - seg;
    const u16* A = seg == 0 ? a0 : (seg == 1 ? a1 : a2);
    const u16* B = seg == 0 ? vt0 : (seg == 1 ? vt1 : vt2);
    const int bx = local % tX;
    const int by = local / tX;

    const int tid = threadIdx.x;
    const int lane = tid & 63;
    const int wave = tid >> 6;
    const int wm = wave >> 1, wn = wave & 1;
    const long m0 = (long)by * 128;     // n (window) rows
    const long n0 = (long)bx * 128;     // d cols

    f32x4 acc[4][4] = {};
    const int lrow = tid >> 2;
    const int lk = (tid & 3) << 3;
    const u16* Ag = A + (m0 + lrow) * (long)K + lk;
    const u16* Bg = B + (n0 + lrow) * (long)K + lk;
    u16* Asl = As + tid * 8;
    u16* Bsl = Bs + tid * 8;
    const long K64 = (long)64 * K;

    for (int k0 = 0; k0 < K; k0 += 32) {
        async_cp16(Ag + k0, Asl);
        async_cp16(Ag + k0 + K64, Asl + 2048);
        async_cp16(Bg + k0, Bsl);
        async_cp16(Bg + k0 + K64, Bsl + 2048);
        __syncthreads();
        bf16x8 af[4], bg[4];
        const int ro = (lane & 15) * 32 + ((lane >> 4) << 3);
#pragma unroll
        for (int i = 0; i < 4; i++) af[i] = *(const bf16x8*)(As + (wm * 64 + i * 16) * 32 + ro);
#pragma unroll
        for (int j = 0; j < 4; j++) bg[j] = *(const bf16x8*)(Bs + (wn * 64 + j * 16) * 32 + ro);
#pragma unroll
        for (int i = 0; i < 4; i++)
#pragma unroll
            for (int j = 0; j < 4; j++)
                acc[i][j] = __builtin_amdgcn_mfma_f32_16x16x32_bf16(af[i], bg[j], acc[i][j], 0, 0, 0);
        __syncthreads();
    }

    // epilogue: restage bf16 tile in LDS, scatter u16x4 runs into Ysp
    u16* Cs = (u16*)smem;
    const int wcm = (1 << l2wc) - 1;
    const int wsm = (1 << l2ws) - 1;
    const int sh = 1 << (l2ws - 1);
    for (int c = 0; c < 2; c++) {
        __syncthreads();
        if (wm == c) {
#pragma unroll
            for (int i = 0; i < 4; i++)
#pragma unroll
                for (int j = 0; j < 4; j++)
#pragma unroll
                    for (int r = 0; r < 4; r++) {
                        const int lr = i * 16 + ((lane >> 4) << 2) + r;
                        Cs[lr * 128 + wn * 64 + j * 16 + (lane & 15)] = f2bf(acc[i][j][r]);
                    }
        }
        __syncthreads();
        const int lr = tid >> 2;
        const int cgbase = (tid & 3) * 32;
        const int n = (int)m0 + c * 64 + lr;
        const int wi = n & wcm;
        const int hi = (n >> l2wc) & wcm;
        const int bb = n >> (2 * l2wc);
        const int rowb = (hi << l2ws) + sh;
        const int colb = (wi << l2ws) + sh;
        const long bbase = (long)bb * 128 * 128 * 192 + 60 * seg;
#pragma unroll
        for (int e = 0; e < 8; e++) {
            const int colg = cgbase + e * 4;
            const int d = (int)n0 + colg;
            if (d < D) {
                const int cc = d % 60;
                const int pp = d / 60;
                const int dh = pp >> l2ws;
                const int dw = pp & wsm;
                const int row = (rowb + dh) & 127;
                const int col = (colb + dw) & 127;
                *(u16x4*)(Ysp + bbase + ((long)row * 128 + col) * 192 + cc) =
                    *(const u16x4*)(Cs + lr * 128 + colg);
            }
        }
    }
}

// ---------------- zero Ysp pad cols 180..191 ----------------
// Ysp aliases the fp32 qq-partials region: fp32 mantissa bits reinterpreted as
// bf16 can encode Inf/NaN; conv2 would compute NaN*0 = NaN. Must run AFTER
// softmax_all (last pG1 read) and before conv2.
__global__ __launch_bounds__(256) void zero_pad(u16* __restrict__ Ysp)
{
    const long r = (long)blockIdx.x * 256 + threadIdx.x;
    u16* p = Ysp + r * 192 + 180;
    const u16x4 z = {0, 0, 0, 0};
    *(u16x4*)(p) = z;
    *(u16x4*)(p + 4) = z;
    *(u16x4*)(p + 8) = z;
}

// ---------------- prep: W1t, W2t, padded biases, accum zero ----------------
__global__ __launch_bounds__(192) void prep_all(
    const float* __restrict__ W1, const float* __restrict__ W2,
    const float* __restrict__ b1, const float* __restrict__ b2,
    u16* __restrict__ W1t, u16* __restrict__ W2t,
    float* __restrict__ b1p, float* __restrict__ b2p, float* __restrict__ accum)
{
    const int bid = blockIdx.x;
    const int t = threadIdx.x;
    if (bid < 384) {
        W1t[bid * 192 + t] = (bid < 360 && t < 180) ? f2bf(W1[t * 360 + bid]) : (u16)0;
    } else if (bid < 640) {
        const int n = bid - 384;
        W2t[n * 192 + t] = (n < 180 && t < 180) ? f2bf(W2[t * 180 + n]) : (u16)0;
    } else {
#pragma unroll
        for (int j = 0; j < 4; j++) {
            const int i = t + 192 * j;
            if (i < 384) b1p[i] = (i < 360) ? b1[i] : 0.0f;
            else if (i < 640) { const int k = i - 384; b2p[k] = (k < 180) ? b2[k] : 0.0f; }
            if (i < 768) accum[i] = 0.0f;
        }
    }
}

// ---------------- BN stats ----------------
__global__ __launch_bounds__(384) void bn_stats(const u16* __restrict__ x, float* __restrict__ accum)
{
    const int ch = threadIdx.x;
    const long base = (long)blockIdx.x * 256 * 384;
    float s = 0.0f, s2 = 0.0f;
    for (int r = 0; r < 256; r++) {
        const float v = bf2f(x[base + (long)r * 384 + ch]);
        s += v; s2 += v * v;
    }
    atomicAdd(&accum[ch], s);
    atomicAdd(&accum[384 + ch], s2);
}

// ---------------- grouped gather + inline BN + transpose ----------------
// blocks: [0,1024) g0 16x64 | [1024,1984) g1 60x16 | [1984,2944) g2 240x4
__global__ __launch_bounds__(256) void gather_all(
    const u16* __restrict__ x, const float* __restrict__ accum,
    const float* __restrict__ bns, const float* __restrict__ bnb,
    u16* __restrict__ q0, u16* __restrict__ q1, u16* __restrict__ q2,
    u16* __restrict__ vt0, u16* __restrict__ vt1, u16* __restrict__ vt2)
{
    __shared__ u16 t[64][65];
    const int bid = blockIdx.x;
    int seg, local;
    if (bid < 1024) { seg = 0; local = bid; }
    else if (bid < 1984) { seg = 1; local = bid - 1024; }
    else { seg = 2; local = bid - 1984; }
    const int tX = seg == 0 ? 16 : (seg == 1 ? 60 : 240);
    const int N = seg == 0 ? 4096 : (seg == 1 ? 1024 : 256);
    const int D = seg == 0 ? 960 : (seg == 1 ? 3840 : 15360);
    const int Dp = seg == 0 ? 1024 : (seg == 1 ? 3840 : 15360);
    const int l2ws = 2 + seg;
    const int l2wc = 5 - seg;
    u16* q = seg == 0 ? q0 : (seg == 1 ? q1 : q2);
    u16* vt = seg == 0 ? vt0 : (seg == 1 ? vt1 : vt2);
    const int bx = local % tX;
    const int by = local / tX;

    const int d0 = bx * 64;
    const int n0 = by * 64;
    const int tc = threadIdx.x & 63;
    const int tr = threadIdx.x >> 6;

    const int d = d0 + tc;
    const int sh = 1 << (l2ws - 1);
    const int cc = d % 60;
    const int pp = d / 60;
    const int dh = pp >> l2ws;
    const int dw = pp & ((1 << l2ws) - 1);
    const int wcm = (1 << l2wc) - 1;
    const int ch = 120 * seg + cc;
    // inline bn_finalize
    const float m_q = accum[ch] * (1.0f / 65536.0f);
    const float v_q = accum[384 + ch] * (1.0f / 65536.0f) - m_q * m_q;
    const float seq = bns[ch] * rsqrtf(v_q + 1e-5f);
    const float beq = bnb[ch] - m_q * seq;
    const float m_v = accum[ch + 60] * (1.0f / 65536.0f);
    const float v_v = accum[384 + ch + 60] * (1.0f / 65536.0f) - m_v * m_v;
    const float sev = bns[ch + 60] * rsqrtf(v_v + 1e-5f);
    const float bev = bnb[ch + 60] - m_v * sev;
    const bool valid = d < D;

#pragma unroll 4
    for (int i = 0; i < 16; i++) {
        const int n = n0 + i * 4 + tr;
        const int wi = n & wcm;
        const int hi = (n >> l2wc) & wcm;
        const int b = n >> (2 * l2wc);
        const int row = ((hi << l2ws) + dh + sh) & 127;
        const int col = ((wi << l2ws) + dw + sh) & 127;
        const long src = ((long)((b << 7) + row) * 128 + col) * 384 + ch;
        const float xq = bf2f(x[src]);
        const float xv = bf2f(x[src + 60]);
        q[(long)n * Dp + d] = valid ? f2bf(seq * xq + beq) : (u16)0;
        t[tc][i * 4 + tr] = f2bf(sev * xv + bev);
    }
    __syncthreads();
#pragma unroll 4
    for (int i = 0; i < 16; i++) {
        const int dd = i * 4 + tr;
        vt[(long)(d0 + dd) * N + n0 + tc] = t[dd][tc];
    }
}

// ---------------- grouped softmax (fused split-K reduce) ----------------
template <int VPT>
__device__ __forceinline__ void softmax_body(
    const float* __restrict__ P, int nsplit, long MN, int rowi,
    float* __restrict__ S, u16* __restrict__ Sb)
{
    const int N = VPT * 256;
    const long base = (long)rowi * N;
    float v[VPT];
    float mx = -3.0e38f;
#pragma unroll
    for (int i = 0; i < VPT; i++) {
        const long idx = base + i * 256 + threadIdx.x;
        float val = P[idx];
        for (int z = 1; z < nsplit; z++) val += P[(long)z * MN + idx];
        v[i] = val; mx = fmaxf(mx, val);
    }
#pragma unroll
    for (int o = 32; o > 0; o >>= 1) mx = fmaxf(mx, __shfl_down(mx, o, 64));
    __shared__ float redm[4];
    if ((threadIdx.x & 63) == 0) redm[threadIdx.x >> 6] = mx;
    __syncthreads();
    mx = fmaxf(fmaxf(redm[0], redm[1]), fmaxf(redm[2], redm[3]));
    float s = 0.0f;
#pragma unroll
    for (int i = 0; i < VPT; i++) { v[i] = __expf(v[i] - mx); s += v[i]; }
#pragma unroll
    for (int o = 32; o > 0; o >>= 1) s += __shfl_down(s, o, 64);
    __shared__ float reds[4];
    if ((threadIdx.x & 63) == 0) reds[threadIdx.x >> 6] = s;
    __syncthreads();
    s = reds[0] + reds[1] + reds[2] + reds[3];
    const float inv = 1.0f / s;
#pragma unroll
    for (int i = 0; i < VPT; i++) {
        const float r = v[i] * inv;
        const long idx = base + i * 256 + threadIdx.x;
        S[idx] = r;
        Sb[idx] = f2bf(r);
    }
}

__global__ __launch_bounds__(256) void softmax_all(
    float* __restrict__ S0, const float* __restrict__ pG1, const float* __restrict__ pG2,
    float* __restrict__ out1, float* __restrict__ out2,
    u16* __restrict__ ab0, u16* __restrict__ ab1, u16* __restrict__ ab2)
{
    const int r = blockIdx.x;
    if (r < 4096)      softmax_body<16>(S0, 1, 16777216L, r, S0, ab0);
    else if (r < 5120) softmax_body<4>(pG1, 8, 1048576L, r - 4096, out1, ab1);
    else               softmax_body<1>(pG2, 60, 65536L, r - 5120, out2, ab2);
}

extern "C" void kernel_launch(void* const* d_in, const int* in_sizes, int n_in,
                              void* d_out, int out_size, void* d_ws, size_t ws_size,
                              hipStream_t stream)
{
    const float* in_x = (const float*)d_in[0];
    const float* w1  = (const float*)d_in[1];
    const float* b1  = (const float*)d_in[2];
    const float* bns = (const float*)d_in[3];
    const float* bnb = (const float*)d_in[4];
    const float* w2  = (const float*)d_in[5];
    const float* b2  = (const float*)d_in[6];
    float* out = (float*)d_out;

    char* w = (char*)d_ws;
    // region0 (33.55 MB): atnb0 (g0 bf16 atn, written by softmax_all, read by pv_all)
    u16* atnb0 = (u16*)w;
    size_t off = 33554432;
    // x region (50.33 MB): x (conv1 out, dead after gather_all)
    //   then qq partials: g1 (8 x 1024^2 x4 = 33.55 MB) at +0, g2 (60 x 256^2 x4 = 15.73 MB) at +33.55 MB
    //   (both dead after softmax_all); then Ysp (25.17 MB) at +0 (zero_pad + pv_all).
    u16* x = (u16*)(w + off);
    float* pG1 = (float*)(w + off);
    float* pG2 = (float*)(w + off + 33554432);
    u16* Ysp = (u16*)(w + off);
    off += 50331648;
    u16* W1t = (u16*)(w + off);  off += 147456;
    u16* W2t = (u16*)(w + off);  off += 98304;
    float* b1p = (float*)(w + off);   off += 4096;
    float* b2p = (float*)(w + off);   off += 4096;
    float* accum = (float*)(w + off); off += 4096;
    u16* q0 = (u16*)(w + off);  off += 8388608;
    u16* q1 = (u16*)(w + off);  off += 7864320;
    u16* q2 = (u16*)(w + off);  off += 7864320;
    u16* vt0 = (u16*)(w + off); off += 8388608;
    u16* vt1 = (u16*)(w + off); off += 7864320;
    u16* vt2 = (u16*)(w + off); off += 7864320;
    u16* atnb1 = (u16*)(w + off); off += 2097152;
    u16* atnb2 = (u16*)(w + off); off += 131072;

    float* S0 = out + 11796480L;   // atn g0 (4096^2)
    float* S1 = out + 28573696L;   // atn g1 (1024^2)
    float* S2 = out + 29622272L;   // atn g2 (256^2)

    prep_all<<<641, 192, 0, stream>>>(w1, w2, b1, b2, W1t, W2t, b1p, b2p, accum);
    conv1_gemm<<<dim3(3, 512), 256, 0, stream>>>(in_x, W1t, x, b1p);
    bn_stats<<<256, 384, 0, stream>>>(x, accum);
    gather_all<<<2944, 256, 0, stream>>>(x, accum, bns, bnb, q0, q1, q2, vt0, vt1, vt2);
    qq_all<<<1776, 256, 0, stream>>>(q0, q1, q2, S0, pG1, pG2);
    softmax_all<<<5376, 256, 0, stream>>>(S0, pG1, pG2, S1, S2, atnb0, atnb1, atnb2);
    zero_pad<<<256, 256, 0, stream>>>(Ysp);
    pv_all<<<736, 256, 0, stream>>>(atnb0, atnb1, atnb2, vt0, vt1, vt2, Ysp);
    gemm_f32<<<dim3(2, 512), 256, 0, stream>>>(Ysp, W2t, out, b2p, 192, 180, 180);
}

// Round 8
// 467.772 us; speedup vs baseline: 1.2980x; 1.0377x over previous
//
#include <hip/hip_runtime.h>

typedef unsigned short u16;
typedef __bf16 bf16x8 __attribute__((ext_vector_type(8)));
typedef float f32x4 __attribute__((ext_vector_type(4)));
typedef u16 u16x4 __attribute__((ext_vector_type(4)));
typedef u16 u16x8 __attribute__((ext_vector_type(8)));

__device__ __forceinline__ u16 f2bf(float v) {
    unsigned u = __float_as_uint(v);
    unsigned r = (u + 0x7fffu + ((u >> 16) & 1u)) >> 16;
    return (u16)r;
}
__device__ __forceinline__ float bf2f(u16 u) { return __uint_as_float(((unsigned)u) << 16); }

__device__ __forceinline__ void async_cp16(const u16* g, u16* l) {
    __builtin_amdgcn_global_load_lds((const __attribute__((address_space(1))) unsigned int*)g,
                                     (__attribute__((address_space(3))) unsigned int*)l, 16, 0, 0);
}

// ---------------- conv2 GEMM (fp32 out, bias, col guard) ----------------
__global__ __launch_bounds__(256) void gemm_f32(
    const u16* __restrict__ A, const u16* __restrict__ B,
    float* __restrict__ C, const float* __restrict__ bias,
    int K, int ldc, int n_store)
{
    __shared__ char smem[16384];
    u16* As = (u16*)smem;
    u16* Bs = (u16*)(smem + 8192);
    const int tid = threadIdx.x;
    const int lane = tid & 63;
    const int wave = tid >> 6;
    const int wm = wave >> 1, wn = wave & 1;
    const long m0 = (long)blockIdx.y * 128;
    const long n0 = (long)blockIdx.x * 128;

    f32x4 acc[4][4] = {};
    const int lrow = tid >> 2;
    const int lk = (tid & 3) << 3;
    const u16* Ag = A + (m0 + lrow) * (long)K + lk;
    const u16* Bg = B + (n0 + lrow) * (long)K + lk;
    u16* Asl = As + tid * 8;
    u16* Bsl = Bs + tid * 8;
    const long K64 = (long)64 * K;

    for (int k0 = 0; k0 < K; k0 += 32) {
        async_cp16(Ag + k0, Asl);
        async_cp16(Ag + k0 + K64, Asl + 2048);
        async_cp16(Bg + k0, Bsl);
        async_cp16(Bg + k0 + K64, Bsl + 2048);
        __syncthreads();
        bf16x8 af[4], bg[4];
        const int ro = (lane & 15) * 32 + ((lane >> 4) << 3);
#pragma unroll
        for (int i = 0; i < 4; i++) af[i] = *(const bf16x8*)(As + (wm * 64 + i * 16) * 32 + ro);
#pragma unroll
        for (int j = 0; j < 4; j++) bg[j] = *(const bf16x8*)(Bs + (wn * 64 + j * 16) * 32 + ro);
#pragma unroll
        for (int i = 0; i < 4; i++)
#pragma unroll
            for (int j = 0; j < 4; j++)
                acc[i][j] = __builtin_amdgcn_mfma_f32_16x16x32_bf16(af[i], bg[j], acc[i][j], 0, 0, 0);
        __syncthreads();
    }

    float bv[4];
#pragma unroll
    for (int j = 0; j < 4; j++) bv[j] = bias[n0 + wn * 64 + j * 16 + (lane & 15)];

    float* Cs = (float*)smem;
    for (int c = 0; c < 4; c++) {
        __syncthreads();
        if (wm == (c >> 1)) {
#pragma unroll
            for (int ii = 0; ii < 2; ii++) {
                const int i = (c & 1) * 2 + ii;
#pragma unroll
                for (int j = 0; j < 4; j++)
#pragma unroll
                    for (int r = 0; r < 4; r++) {
                        const int lr = ii * 16 + ((lane >> 4) << 2) + r;
                        Cs[lr * 128 + wn * 64 + j * 16 + (lane & 15)] = acc[i][j][r] + bv[j];
                    }
            }
        }
        __syncthreads();
        const int lr = tid >> 3;
        const int cg = (tid & 7) * 16;
        const long rowg = m0 + c * 32 + lr;
#pragma unroll
        for (int e = 0; e < 4; e++) {
            const int colg = cg + e * 4;
            if ((int)n0 + colg < n_store)
                *(f32x4*)(C + rowg * (long)ldc + n0 + colg) = *(const f32x4*)(Cs + lr * 128 + colg);
        }
    }
}

// ---------------- conv1 fused: x = fp32 A(65536x180, K pad 192) @ W1t^T + b1 ----------------
__global__ __launch_bounds__(256) void conv1_gemm(
    const float* __restrict__ A, const u16* __restrict__ B,
    u16* __restrict__ C, const float* __restrict__ bias)
{
    __shared__ char smem[16384];
    u16* As = (u16*)smem;
    u16* Bs = (u16*)(smem + 8192);
    const int tid = threadIdx.x;
    const int lane = tid & 63;
    const int wave = tid >> 6;
    const int wm = wave >> 1, wn = wave & 1;
    const long m0 = (long)blockIdx.y * 128;
    const long n0 = (long)blockIdx.x * 128;

    f32x4 acc[4][4] = {};
    const int lrow = tid >> 2;
    const int lk = (tid & 3) << 3;
    const float* Ar0 = A + (m0 + lrow) * 180L;
    const float* Ar1 = Ar0 + 64 * 180L;
    const u16* Bg = B + (n0 + lrow) * 192L + lk;
    u16* Asl = As + tid * 8;
    u16* Bsl = Bs + tid * 8;

#pragma unroll
    for (int k0 = 0; k0 < 192; k0 += 32) {
        const int gk = k0 + lk;
        u16x8 oa, ob;
        if (gk + 8 <= 180) {
            f32x4 a0 = *(const f32x4*)(Ar0 + gk), a1 = *(const f32x4*)(Ar0 + gk + 4);
            f32x4 b0 = *(const f32x4*)(Ar1 + gk), b1 = *(const f32x4*)(Ar1 + gk + 4);
#pragma unroll
            for (int c = 0; c < 4; c++) {
                oa[c] = f2bf(a0[c]); oa[4 + c] = f2bf(a1[c]);
                ob[c] = f2bf(b0[c]); ob[4 + c] = f2bf(b1[c]);
            }
        } else if (gk < 180) {   // gk == 176
            f32x4 a0 = *(const f32x4*)(Ar0 + gk);
            f32x4 b0 = *(const f32x4*)(Ar1 + gk);
#pragma unroll
            for (int c = 0; c < 4; c++) {
                oa[c] = f2bf(a0[c]); oa[4 + c] = 0;
                ob[c] = f2bf(b0[c]); ob[4 + c] = 0;
            }
        } else {
#pragma unroll
            for (int c = 0; c < 8; c++) { oa[c] = 0; ob[c] = 0; }
        }
        *(u16x8*)Asl = oa;
        *(u16x8*)(Asl + 2048) = ob;
        async_cp16(Bg + k0, Bsl);
        async_cp16(Bg + k0 + 64 * 192, Bsl + 2048);
        __syncthreads();
        bf16x8 af[4], bg[4];
        const int ro = (lane & 15) * 32 + ((lane >> 4) << 3);
#pragma unroll
        for (int i = 0; i < 4; i++) af[i] = *(const bf16x8*)(As + (wm * 64 + i * 16) * 32 + ro);
#pragma unroll
        for (int j = 0; j < 4; j++) bg[j] = *(const bf16x8*)(Bs + (wn * 64 + j * 16) * 32 + ro);
#pragma unroll
        for (int i = 0; i < 4; i++)
#pragma unroll
            for (int j = 0; j < 4; j++)
                acc[i][j] = __builtin_amdgcn_mfma_f32_16x16x32_bf16(af[i], bg[j], acc[i][j], 0, 0, 0);
        __syncthreads();
    }

    float bv[4];
#pragma unroll
    for (int j = 0; j < 4; j++) bv[j] = bias[n0 + wn * 64 + j * 16 + (lane & 15)];

    u16* Cs = (u16*)smem;
    for (int c = 0; c < 2; c++) {
        __syncthreads();
        if (wm == c) {
#pragma unroll
            for (int i = 0; i < 4; i++)
#pragma unroll
                for (int j = 0; j < 4; j++)
#pragma unroll
                    for (int r = 0; r < 4; r++) {
                        const int lr = i * 16 + ((lane >> 4) << 2) + r;
                        Cs[lr * 128 + wn * 64 + j * 16 + (lane & 15)] = f2bf(acc[i][j][r] + bv[j]);
                    }
        }
        __syncthreads();
        const int lr = tid >> 2;
        const int cg = (tid & 3) * 32;
        const long rowg = m0 + c * 64 + lr;
#pragma unroll
        for (int e = 0; e < 4; e++) {
            const int colg = cg + e * 8;
            *(u16x8*)(C + rowg * 384L + n0 + colg) = *(const u16x8*)(Cs + lr * 128 + colg);
        }
    }
}

// ---------------- grouped qq^T: all 3 groups + split-K in ONE dispatch ----------------
// blocks: [0,1024) g0 32x32 z=1 | [1024,1536) g1 8x8 z=8 | [1536,1776) g2 2x2 z=60
__global__ __launch_bounds__(256) void qq_all(
    const u16* __restrict__ q0, const u16* __restrict__ q1, const u16* __restrict__ q2,
    float* __restrict__ S0, float* __restrict__ pG1, float* __restrict__ pG2)
{
    __shared__ char smem[16384];
    u16* As = (u16*)smem;
    u16* Bs = (u16*)(smem + 8192);
    const int bid = blockIdx.x;
    int seg, local;
    if (bid < 1024) { seg = 0; local = bid; }
    else if (bid < 1536) { seg = 1; local = bid - 1024; }
    else { seg = 2; local = bid - 1536; }
    const int tX = seg == 0 ? 32 : (seg == 1 ? 8 : 2);
    const int tt = tX * tX;
    const int K = seg == 0 ? 1024 : (seg == 1 ? 3840 : 15360);
    const int Ksplit = seg == 0 ? 1024 : (seg == 1 ? 480 : 256);
    const int N = seg == 0 ? 4096 : (seg == 1 ? 1024 : 256);
    const u16* A = seg == 0 ? q0 : (seg == 1 ? q1 : q2);
    float* outP = seg == 0 ? S0 : (seg == 1 ? pG1 : pG2);
    const int z = local / tt;
    const int rem = local - z * tt;
    const int bx = rem % tX;
    const int by = rem / tX;

    const int tid = threadIdx.x;
    const int lane = tid & 63;
    const int wave = tid >> 6;
    const int wm = wave >> 1, wn = wave & 1;
    const long m0 = (long)by * 128;
    const long n0 = (long)bx * 128;
    const int kbeg = z * Ksplit;

    f32x4 acc[4][4] = {};
    const int lrow = tid >> 2;
    const int lk = (tid & 3) << 3;
    const u16* Ag = A + (m0 + lrow) * (long)K + lk;
    const u16* Bg = A + (n0 + lrow) * (long)K + lk;
    u16* Asl = As + tid * 8;
    u16* Bsl = Bs + tid * 8;
    const long K64 = (long)64 * K;

    for (int k0 = kbeg; k0 < kbeg + Ksplit; k0 += 32) {
        async_cp16(Ag + k0, Asl);
        async_cp16(Ag + k0 + K64, Asl + 2048);
        async_cp16(Bg + k0, Bsl);
        async_cp16(Bg + k0 + K64, Bsl + 2048);
        __syncthreads();
        bf16x8 af[4], bg[4];
        const int ro = (lane & 15) * 32 + ((lane >> 4) << 3);
#pragma unroll
        for (int i = 0; i < 4; i++) af[i] = *(const bf16x8*)(As + (wm * 64 + i * 16) * 32 + ro);
#pragma unroll
        for (int j = 0; j < 4; j++) bg[j] = *(const bf16x8*)(Bs + (wn * 64 + j * 16) * 32 + ro);
#pragma unroll
        for (int i = 0; i < 4; i++)
#pragma unroll
            for (int j = 0; j < 4; j++)
                acc[i][j] = __builtin_amdgcn_mfma_f32_16x16x32_bf16(af[i], bg[j], acc[i][j], 0, 0, 0);
        __syncthreads();
    }

    float* Pz = outP + (long)z * N * N;
    float* Cs = (float*)smem;
    for (int c = 0; c < 4; c++) {
        __syncthreads();
        if (wm == (c >> 1)) {
#pragma unroll
            for (int ii = 0; ii < 2; ii++) {
                const int i = (c & 1) * 2 + ii;
#pragma unroll
                for (int j = 0; j < 4; j++)
#pragma unroll
                    for (int r = 0; r < 4; r++) {
                        const int lr = ii * 16 + ((lane >> 4) << 2) + r;
                        Cs[lr * 128 + wn * 64 + j * 16 + (lane & 15)] = acc[i][j][r];
                    }
            }
        }
        __syncthreads();
        const int lr = tid >> 3;
        const int cg = (tid & 7) * 16;
        const long rowg = m0 + c * 32 + lr;
#pragma unroll
        for (int e = 0; e < 4; e++) {
            const int colg = cg + e * 4;
            *(f32x4*)(Pz + rowg * (long)N + n0 + colg) = *(const f32x4*)(Cs + lr * 128 + colg);
        }
    }
}

// ---------------- grouped PV ----------------
// blocks: [0,512) g0 8x32 split-K z=2 (fp32 partials) | [512,752) g1 30x8 | [752,992) g2 120x2
// g1/g2 scatter bf16 directly into Ysp; g0 writes partials, reduced by reduce_scatter_g0.
__global__ __launch_bounds__(256, 4) void pv_all(
    const u16* __restrict__ a0, const u16* __restrict__ a1, const u16* __restrict__ a2,
    const u16* __restrict__ vt0, const u16* __restrict__ vt1, const u16* __restrict__ vt2,
    u16* __restrict__ Ysp, float* __restrict__ pP0, float* __restrict__ pP1)
{
    __shared__ char smem[16384];
    u16* As = (u16*)smem;
    u16* Bs = (u16*)(smem + 8192);
    const int bid = blockIdx.x;
    int seg, local, z = 0;
    if (bid < 512) { seg = 0; z = bid >> 8; local = bid & 255; }
    else if (bid < 752) { seg = 1; local = bid - 512; }
    else { seg = 2; local = bid - 752; }
    const int tX = seg == 0 ? 8 : (seg == 1 ? 30 : 120);
    const int K = seg == 0 ? 4096 : (seg == 1 ? 1024 : 256);
    const int Ksplit = seg == 0 ? 2048 : K;
    const int D = seg == 0 ? 960 : (seg == 1 ? 3840 : 15360);
    const int l2ws = 2 + seg;
    const int l2wc = 5 - seg;
    const u16* A = seg == 0 ? a0 : (seg == 1 ? a1 : a2);
    const u16* B = seg == 0 ? vt0 : (seg == 1 ? vt1 : vt2);
    const int bx = local % tX;
    const int by = local / tX;

    const int tid = threadIdx.x;
    const int lane = tid & 63;
    const int wave = tid >> 6;
    const int wm = wave >> 1, wn = wave & 1;
    const long m0 = (long)by * 128;     // n (window) rows
    const long n0 = (long)bx * 128;     // d cols
    const int kbeg = z * Ksplit;

    f32x4 acc[4][4] = {};
    const int lrow = tid >> 2;
    const int lk = (tid & 3) << 3;
    const u16* Ag = A + (m0 + lrow) * (long)K + lk;
    const u16* Bg = B + (n0 + lrow) * (long)K + lk;
    u16* Asl = As + tid * 8;
    u16* Bsl = Bs + tid * 8;
    const long K64 = (long)64 * K;

    for (int k0 = kbeg; k0 < kbeg + Ksplit; k0 += 32) {
        async_cp16(Ag + k0, Asl);
        async_cp16(Ag + k0 + K64, Asl + 2048);
        async_cp16(Bg + k0, Bsl);
        async_cp16(Bg + k0 + K64, Bsl + 2048);
        __syncthreads();
        bf16x8 af[4], bg[4];
        const int ro = (lane & 15) * 32 + ((lane >> 4) << 3);
#pragma unroll
        for (int i = 0; i < 4; i++) af[i] = *(const bf16x8*)(As + (wm * 64 + i * 16) * 32 + ro);
#pragma unroll
        for (int j = 0; j < 4; j++) bg[j] = *(const bf16x8*)(Bs + (wn * 64 + j * 16) * 32 + ro);
#pragma unroll
        for (int i = 0; i < 4; i++)
#pragma unroll
            for (int j = 0; j < 4; j++)
                acc[i][j] = __builtin_amdgcn_mfma_f32_16x16x32_bf16(af[i], bg[j], acc[i][j], 0, 0, 0);
        __syncthreads();
    }

    if (seg == 0) {
        // fp32 partial write (4096 x 1024 row-major), coalesced via LDS restage
        float* Pz = (z == 0) ? pP0 : pP1;
        float* Cs = (float*)smem;
        for (int c = 0; c < 4; c++) {
            __syncthreads();
            if (wm == (c >> 1)) {
#pragma unroll
                for (int ii = 0; ii < 2; ii++) {
                    const int i = (c & 1) * 2 + ii;
#pragma unroll
                    for (int j = 0; j < 4; j++)
#pragma unroll
                        for (int r = 0; r < 4; r++) {
                            const int lr = ii * 16 + ((lane >> 4) << 2) + r;
                            Cs[lr * 128 + wn * 64 + j * 16 + (lane & 15)] = acc[i][j][r];
                        }
                }
            }
            __syncthreads();
            const int lr = tid >> 3;
            const int cg = (tid & 7) * 16;
            const long rowg = m0 + c * 32 + lr;
#pragma unroll
            for (int e = 0; e < 4; e++) {
                const int colg = cg + e * 4;
                *(f32x4*)(Pz + rowg * 1024L + n0 + colg) = *(const f32x4*)(Cs + lr * 128 + colg);
            }
        }
        return;
    }

    // g1/g2: bf16 scatter epilogue
    u16* Cs = (u16*)smem;
    const int wcm = (1 << l2wc) - 1;
    const int wsm = (1 << l2ws) - 1;
    const int sh = 1 << (l2ws - 1);
    for (int c = 0; c < 2; c++) {
        __syncthreads();
        if (wm == c) {
#pragma unroll
            for (int i = 0; i < 4; i++)
#pragma unroll
                for (int j = 0; j < 4; j++)
#pragma unroll
                    for (int r = 0; r < 4; r++) {
                        const int lr = i * 16 + ((lane >> 4) << 2) + r;
                        Cs[lr * 128 + wn * 64 + j * 16 + (lane & 15)] = f2bf(acc[i][j][r]);
                    }
        }
        __syncthreads();
        const int lr = tid >> 2;
        const int cgbase = (tid & 3) * 32;
        const int n = (int)m0 + c * 64 + lr;
        const int wi = n & wcm;
        const int hi = (n >> l2wc) & wcm;
        const int bb = n >> (2 * l2wc);
        const int rowb = (hi << l2ws) + sh;
        const int colb = (wi << l2ws) + sh;
        const long bbase = (long)bb * 128 * 128 * 192 + 60 * seg;
#pragma unroll
        for (int e = 0; e < 8; e++) {
            const int colg = cgbase + e * 4;
            const int d = (int)n0 + colg;
            if (d < D) {
                const int cc = d % 60;
                const int pp = d / 60;
                const int dh = pp >> l2ws;
                const int dw = pp & wsm;
                const int row = (rowb + dh) & 127;
                const int col = (colb + dw) & 127;
                *(u16x4*)(Ysp + bbase + ((long)row * 128 + col) * 192 + cc) =
                    *(const u16x4*)(Cs + lr * 128 + colg);
            }
        }
    }
}

// ---------------- g0 split-K reduce + windowed scatter into Ysp ----------------
// grid = 4096 (one block per window row n), 256 threads x 4 d-elems.
__global__ __launch_bounds__(256) void reduce_scatter_g0(
    const float* __restrict__ pP0, const float* __restrict__ pP1, u16* __restrict__ Ysp)
{
    const int n = blockIdx.x;
    const int d = threadIdx.x * 4;
    if (d >= 960) return;
    const long i = (long)n * 1024 + d;
    f32x4 s = *(const f32x4*)(pP0 + i) + *(const f32x4*)(pP1 + i);
    const int cc = d % 60;
    const int pp = d / 60;
    const int dh = pp >> 2;
    const int dw = pp & 3;
    const int wi = n & 31;
    const int hi = (n >> 5) & 31;
    const int b = n >> 10;
    const int row = ((hi << 2) + dh + 2) & 127;
    const int col = ((wi << 2) + dw + 2) & 127;
    u16x4 o;
#pragma unroll
    for (int c = 0; c < 4; c++) o[c] = f2bf(s[c]);
    *(u16x4*)(Ysp + ((long)((b << 7) + row) * 128 + col) * 192 + cc) = o;
}

// ---------------- zero Ysp pad cols 180..191 ----------------
__global__ __launch_bounds__(256) void zero_pad(u16* __restrict__ Ysp)
{
    const long r = (long)blockIdx.x * 256 + threadIdx.x;
    u16* p = Ysp + r * 192 + 180;
    const u16x4 z = {0, 0, 0, 0};
    *(u16x4*)(p) = z;
    *(u16x4*)(p + 4) = z;
    *(u16x4*)(p + 8) = z;
}

// ---------------- prep: W1t, W2t, padded biases, accum zero ----------------
__global__ __launch_bounds__(192) void prep_all(
    const float* __restrict__ W1, const float* __restrict__ W2,
    const float* __restrict__ b1, const float* __restrict__ b2,
    u16* __restrict__ W1t, u16* __restrict__ W2t,
    float* __restrict__ b1p, float* __restrict__ b2p, float* __restrict__ accum)
{
    const int bid = blockIdx.x;
    const int t = threadIdx.x;
    if (bid < 384) {
        W1t[bid * 192 + t] = (bid < 360 && t < 180) ? f2bf(W1[t * 360 + bid]) : (u16)0;
    } else if (bid < 640) {
        const int n = bid - 384;
        W2t[n * 192 + t] = (n < 180 && t < 180) ? f2bf(W2[t * 180 + n]) : (u16)0;
    } else {
#pragma unroll
        for (int j = 0; j < 4; j++) {
            const int i = t + 192 * j;
            if (i < 384) b1p[i] = (i < 360) ? b1[i] : 0.0f;
            else if (i < 640) { const int k = i - 384; b2p[k] = (k < 180) ? b2[k] : 0.0f; }
            if (i < 768) accum[i] = 0.0f;
        }
    }
}

// ---------------- BN stats ----------------
__global__ __launch_bounds__(384) void bn_stats(const u16* __restrict__ x, float* __restrict__ accum)
{
    const int ch = threadIdx.x;
    const long base = (long)blockIdx.x * 256 * 384;
    float s = 0.0f, s2 = 0.0f;
    for (int r = 0; r < 256; r++) {
        const float v = bf2f(x[base + (long)r * 384 + ch]);
        s += v; s2 += v * v;
    }
    atomicAdd(&accum[ch], s);
    atomicAdd(&accum[384 + ch], s2);
}

// ---------------- grouped gather + inline BN + transpose ----------------
// blocks: [0,1024) g0 16x64 | [1024,1984) g1 60x16 | [1984,2944) g2 240x4
__global__ __launch_bounds__(256) void gather_all(
    const u16* __restrict__ x, const float* __restrict__ accum,
    const float* __restrict__ bns, const float* __restrict__ bnb,
    u16* __restrict__ q0, u16* __restrict__ q1, u16* __restrict__ q2,
    u16* __restrict__ vt0, u16* __restrict__ vt1, u16* __restrict__ vt2)
{
    __shared__ u16 t[64][65];
    const int bid = blockIdx.x;
    int seg, local;
    if (bid < 1024) { seg = 0; local = bid; }
    else if (bid < 1984) { seg = 1; local = bid - 1024; }
    else { seg = 2; local = bid - 1984; }
    const int tX = seg == 0 ? 16 : (seg == 1 ? 60 : 240);
    const int N = seg == 0 ? 4096 : (seg == 1 ? 1024 : 256);
    const int D = seg == 0 ? 960 : (seg == 1 ? 3840 : 15360);
    const int Dp = seg == 0 ? 1024 : (seg == 1 ? 3840 : 15360);
    const int l2ws = 2 + seg;
    const int l2wc = 5 - seg;
    u16* q = seg == 0 ? q0 : (seg == 1 ? q1 : q2);
    u16* vt = seg == 0 ? vt0 : (seg == 1 ? vt1 : vt2);
    const int bx = local % tX;
    const int by = local / tX;

    const int d0 = bx * 64;
    const int n0 = by * 64;
    const int tc = threadIdx.x & 63;
    const int tr = threadIdx.x >> 6;

    const int d = d0 + tc;
    const int sh = 1 << (l2ws - 1);
    const int cc = d % 60;
    const int pp = d / 60;
    const int dh = pp >> l2ws;
    const int dw = pp & ((1 << l2ws) - 1);
    const int wcm = (1 << l2wc) - 1;
    const int ch = 120 * seg + cc;
    // inline bn_finalize
    const float m_q = accum[ch] * (1.0f / 65536.0f);
    const float v_q = accum[384 + ch] * (1.0f / 65536.0f) - m_q * m_q;
    const float seq = bns[ch] * rsqrtf(v_q + 1e-5f);
    const float beq = bnb[ch] - m_q * seq;
    const float m_v = accum[ch + 60] * (1.0f / 65536.0f);
    const float v_v = accum[384 + ch + 60] * (1.0f / 65536.0f) - m_v * m_v;
    const float sev = bns[ch + 60] * rsqrtf(v_v + 1e-5f);
    const float bev = bnb[ch + 60] - m_v * sev;
    const bool valid = d < D;

#pragma unroll 4
    for (int i = 0; i < 16; i++) {
        const int n = n0 + i * 4 + tr;
        const int wi = n & wcm;
        const int hi = (n >> l2wc) & wcm;
        const int b = n >> (2 * l2wc);
        const int row = ((hi << l2ws) + dh + sh) & 127;
        const int col = ((wi << l2ws) + dw + sh) & 127;
        const long src = ((long)((b << 7) + row) * 128 + col) * 384 + ch;
        const float xq = bf2f(x[src]);
        const float xv = bf2f(x[src + 60]);
        q[(long)n * Dp + d] = valid ? f2bf(seq * xq + beq) : (u16)0;
        t[tc][i * 4 + tr] = f2bf(sev * xv + bev);
    }
    __syncthreads();
#pragma unroll 4
    for (int i = 0; i < 16; i++) {
        const int dd = i * 4 + tr;
        vt[(long)(d0 + dd) * N + n0 + tc] = t[dd][tc];
    }
}

// ---------------- grouped softmax (fused split-K reduce) ----------------
template <int VPT>
__device__ __forceinline__ void softmax_body(
    const float* __restrict__ P, int nsplit, long MN, int rowi,
    float* __restrict__ S, u16* __restrict__ Sb)
{
    const int N = VPT * 256;
    const long base = (long)rowi * N;
    float v[VPT];
    float mx = -3.0e38f;
#pragma unroll
    for (int i = 0; i < VPT; i++) {
        const long idx = base + i * 256 + threadIdx.x;
        float val = P[idx];
        for (int z = 1; z < nsplit; z++) val += P[(long)z * MN + idx];
        v[i] = val; mx = fmaxf(mx, val);
    }
#pragma unroll
    for (int o = 32; o > 0; o >>= 1) mx = fmaxf(mx, __shfl_down(mx, o, 64));
    __shared__ float redm[4];
    if ((threadIdx.x & 63) == 0) redm[threadIdx.x >> 6] = mx;
    __syncthreads();
    mx = fmaxf(fmaxf(redm[0], redm[1]), fmaxf(redm[2], redm[3]));
    float s = 0.0f;
#pragma unroll
    for (int i = 0; i < VPT; i++) { v[i] = __expf(v[i] - mx); s += v[i]; }
#pragma unroll
    for (int o = 32; o > 0; o >>= 1) s += __shfl_down(s, o, 64);
    __shared__ float reds[4];
    if ((threadIdx.x & 63) == 0) reds[threadIdx.x >> 6] = s;
    __syncthreads();
    s = reds[0] + reds[1] + reds[2] + reds[3];
    const float inv = 1.0f / s;
#pragma unroll
    for (int i = 0; i < VPT; i++) {
        const float r = v[i] * inv;
        const long idx = base + i * 256 + threadIdx.x;
        S[idx] = r;
        Sb[idx] = f2bf(r);
    }
}

__global__ __launch_bounds__(256) void softmax_all(
    float* __restrict__ S0, const float* __restrict__ pG1, const float* __restrict__ pG2,
    float* __restrict__ out1, float* __restrict__ out2,
    u16* __restrict__ ab0, u16* __restrict__ ab1, u16* __restrict__ ab2)
{
    const int r = blockIdx.x;
    if (r < 4096)      softmax_body<16>(S0, 1, 16777216L, r, S0, ab0);
    else if (r < 5120) softmax_body<4>(pG1, 8, 1048576L, r - 4096, out1, ab1);
    else               softmax_body<1>(pG2, 60, 65536L, r - 5120, out2, ab2);
}

extern "C" void kernel_launch(void* const* d_in, const int* in_sizes, int n_in,
                              void* d_out, int out_size, void* d_ws, size_t ws_size,
                              hipStream_t stream)
{
    const float* in_x = (const float*)d_in[0];
    const float* w1  = (const float*)d_in[1];
    const float* b1  = (const float*)d_in[2];
    const float* bns = (const float*)d_in[3];
    const float* bnb = (const float*)d_in[4];
    const float* w2  = (const float*)d_in[5];
    const float* b2  = (const float*)d_in[6];
    float* out = (float*)d_out;

    char* w = (char*)d_ws;
    // region0 (33.55 MB): atnb0 (g0 bf16 atn, softmax_all -> pv_all)
    u16* atnb0 = (u16*)w;
    size_t off = 33554432;
    // x region (50.33 MB): x (conv1 out, dead after gather_all);
    //   then qq partials pG1 (33.55 @ +0), pG2 (15.73 @ +33.55) [dead after softmax_all];
    //   then Ysp (25.17 @ +0) and pP1 (g0 PV partial z1, 16.78 @ +25.17).
    u16* x = (u16*)(w + off);
    float* pG1 = (float*)(w + off);
    float* pG2 = (float*)(w + off + 33554432);
    u16* Ysp = (u16*)(w + off);
    float* pP1 = (float*)(w + off + 25165824);
    off += 50331648;
    u16* W1t = (u16*)(w + off);  off += 147456;
    u16* W2t = (u16*)(w + off);  off += 98304;
    float* b1p = (float*)(w + off);   off += 4096;
    float* b2p = (float*)(w + off);   off += 4096;
    float* accum = (float*)(w + off); off += 4096;
    u16* q0 = (u16*)(w + off);  off += 8388608;
    u16* q1 = (u16*)(w + off);  off += 7864320;
    u16* q2 = (u16*)(w + off);  off += 7864320;
    u16* vt0 = (u16*)(w + off); off += 8388608;
    u16* vt1 = (u16*)(w + off); off += 7864320;
    u16* vt2 = (u16*)(w + off); off += 7864320;
    u16* atnb1 = (u16*)(w + off); off += 2097152;
    u16* atnb2 = (u16*)(w + off); off += 131072;
    // pP0 (g0 PV partial z0, 16.78 MB) overlays dead q0/q1/q2 (24.1 MB)
    float* pP0 = (float*)q0;

    float* S0 = out + 11796480L;   // atn g0 (4096^2)
    float* S1 = out + 28573696L;   // atn g1 (1024^2)
    float* S2 = out + 29622272L;   // atn g2 (256^2)

    prep_all<<<641, 192, 0, stream>>>(w1, w2, b1, b2, W1t, W2t, b1p, b2p, accum);
    conv1_gemm<<<dim3(3, 512), 256, 0, stream>>>(in_x, W1t, x, b1p);
    bn_stats<<<256, 384, 0, stream>>>(x, accum);
    gather_all<<<2944, 256, 0, stream>>>(x, accum, bns, bnb, q0, q1, q2, vt0, vt1, vt2);
    qq_all<<<1776, 256, 0, stream>>>(q0, q1, q2, S0, pG1, pG2);
    softmax_all<<<5376, 256, 0, stream>>>(S0, pG1, pG2, S1, S2, atnb0, atnb1, atnb2);
    zero_pad<<<256, 256, 0, stream>>>(Ysp);
    pv_all<<<992, 256, 0, stream>>>(atnb0, atnb1, atnb2, vt0, vt1, vt2, Ysp, pP0, pP1);
    reduce_scatter_g0<<<4096, 256, 0, stream>>>(pP0, pP1, Ysp);
    gemm_f32<<<dim3(2, 512), 256, 0, stream>>>(Ysp, W2t, out, b2p, 192, 180, 180);
}